// Round 12
// baseline (285.142 us; speedup 1.0000x reference)
//
#include <hip/hip_runtime.h>

#define HW 15200
#define SSD 54
#define NBATCH 4
#define NNODE 566
#define NPAD 576
#define CGD 256
#define CDD 512
#define NSPLIT 95
#define KSPAN 160   // 15200/95
#define NGRP (NSPLIT*NBATCH)          // 380
#define CCBLK 3072                    // ceil(380/8)*64

typedef __attribute__((ext_vector_type(4))) float f32x4;
typedef __attribute__((ext_vector_type(8))) short bf16x8;
typedef unsigned short ushort_t;

// BT sub-offsets (ushort units)
#define BT_RIN   0
#define BT_SIN   262144
#define BT_HEADS 393216
#define BT_GOUT  458752
#define BT_ROUT  524288
#define BT_SOUT  589824
#define BT_SEG2  622592
#define BT_TOTAL 630784

// ---------------- ws layout (float units) ----------------
static constexpr long OFF_P     = 0;                                    // (unused — P computed inline)
static constexpr long OFF_CC    = OFF_P     + (long)NBATCH*SSD*HW;      // fp32 ccp [4][64][512] (atomic acc)
static constexpr long OFF_NODES = OFF_CC    + (long)NBATCH*64*CDD;      // bf16 [4][566][256]
static constexpr long OFF_WH    = OFF_NODES + (long)NBATCH*NNODE*CGD;   // WhT bf16 [16][64][576]
static constexpr long OFF_S1    = OFF_WH    + (long)16*NNODE*64;
static constexpr long OFF_S2    = OFF_S1    + 16*NPAD;
static constexpr long OFF_X     = OFF_S2    + 16*NPAD;                  // bf16 [4][566][256]
static constexpr long OFF_WH2   = OFF_X     + (long)NBATCH*NNODE*CGD;   // WhT2 bf16 [4][256][576]
static constexpr long OFF_S1B   = OFF_WH2   + (long)NBATCH*NNODE*CGD;   // fp32 [4][576] (atomic acc)
static constexpr long OFF_S2B   = OFF_S1B   + NBATCH*NPAD;              // fp32 [4][576] (atomic acc)
static constexpr long OFF_G     = OFF_S2B   + NBATCH*NPAD;              // bf16 [4][566][256]
static constexpr long OFF_SUMS  = OFF_G     + (long)NBATCH*NNODE*CGD;   // fp32 [4][64] softmax row sums (atomic)
static constexpr long OFF_BT    = OFF_SUMS  + 256;                      // bf16 transposed weights
static constexpr long OFF_ASEG  = OFF_BT    + (BT_TOTAL/2 + 8);         // bf16 Aseg [4][64][576]
static constexpr long OFF_SEG   = OFF_ASEG  + (long)NBATCH*64*576/2;    // segb fp32 [4][54][HW]
static constexpr long OFF_RFB   = OFF_SEG   + (long)NBATCH*SSD*HW;      // bf16 region_f [2048][1024]
static constexpr long OFF_WCOMB = OFF_RFB   + 1048576;                  // bf16 [64][256] W_sout@Wseg2 ^T
static constexpr long OFF_B2    = OFF_WCOMB + 8192;                     // fp32 [64] b_sout@Wseg2
static constexpr long OFF_ATTNB = OFF_B2    + 64;                       // bf16 attn [4][64][HW]

__device__ inline float lrelu04(float x){ return x >= 0.f ? x : 0.4f*x; }
__device__ inline float eluf(float x){ return x > 0.f ? x : __expf(x) - 1.f; }
__device__ inline ushort_t f2bf(float f){
    unsigned u = __float_as_uint(f);
    return (ushort_t)((u + 0x7FFFu + ((u >> 16) & 1u)) >> 16);
}
__device__ inline float bf2f(ushort_t u){ return __uint_as_float((unsigned)u << 16); }
__device__ inline bf16x8 pack8(float4 lo, float4 hi){
    union { bf16x8 v; ushort_t u[8]; } p;
    p.u[0]=f2bf(lo.x); p.u[1]=f2bf(lo.y); p.u[2]=f2bf(lo.z); p.u[3]=f2bf(lo.w);
    p.u[4]=f2bf(hi.x); p.u[5]=f2bf(hi.y); p.u[6]=f2bf(hi.z); p.u[7]=f2bf(hi.w);
    return p.v;
}

// ---------------- kernel 0: zero ccp + s1b/s2b + sums (atomic accumulators) ----------------
__global__ __launch_bounds__(256)
void zero_init(float* __restrict__ ccp, float* __restrict__ s1s2b,
               float* __restrict__ sums)
{
    long i = (long)blockIdx.x*256 + threadIdx.x;
    if (i < (long)NBATCH*64*CDD) { ccp[i] = 0.f; return; }
    i -= (long)NBATCH*64*CDD;
    if (i < 2L*NBATCH*NPAD) { s1s2b[i] = 0.f; return; }
    i -= 2L*NBATCH*NPAD;
    if (i < 256) sums[i] = 0.f;
}

// ---------------- kernel 1: cc_mfma (inline exp(score), atomic split-K, NSPLIT=95) + prep ----------------
// bid < CCBLK: class_center MFMA. 3040 active blocks (~47 waves/CU) — latency-hiding width.
// XCD-grouped (bid%8): the 8 nt-blocks sharing one score k-slice land on the SAME XCD L2.
// nt==0/w==0 blocks also accumulate softmax row-sums atomically.
// bid >= CCBLK: attn per-pixel softmax, region copy, bf16 weight transposes, Wcomb/bias2.
__global__ __launch_bounds__(256)
void cc_prep(const float* __restrict__ stuff,
             ushort_t* __restrict__ sbout, float* __restrict__ ccp,
             float* __restrict__ sums,
             const float* __restrict__ score, ushort_t* __restrict__ attnb,
             const float* __restrict__ rf, float* __restrict__ out_region,
             ushort_t* __restrict__ rfb,
             const float* __restrict__ W_seg, ushort_t* __restrict__ asegb,
             const float* __restrict__ W_rin, const float* __restrict__ W_sin,
             const float* __restrict__ W_heads, const float* __restrict__ W_gout,
             const float* __restrict__ W_rout, const float* __restrict__ W_sout,
             const float* __restrict__ b_sout,
             ushort_t* __restrict__ bt, ushort_t* __restrict__ wcomb,
             float* __restrict__ bias2)
{
    int bid = blockIdx.x;
    if (bid < CCBLK) {
        int g = (bid >> 6) * 8 + (bid & 7);    // group = (ks,b), 0..379 (+4 idle)
        if (g >= NGRP) return;
        int nt = (bid >> 3) & 7;
        int ks = g >> 2, b = g & 3;

        int w = threadIdx.x >> 6, l = threadIdx.x & 63;
        int lr = l & 15, lk = l >> 4;
        int n0 = nt*64 + w*16;
        const float* Srow = stuff + ((long)b*CDD + n0 + lr)*HW;
        ushort_t*    Sout = sbout + ((long)b*CDD + n0 + lr)*HW;
        f32x4 acc[4] = {};
        float rsum[4] = {0.f, 0.f, 0.f, 0.f};
        int kbeg = ks * KSPAN;
        #pragma unroll
        for (int k0 = kbeg; k0 < kbeg + KSPAN; k0 += 32) {
            int kk = k0 + lk*8;
            float4 lo = *(const float4*)&Srow[kk];
            float4 hi = *(const float4*)&Srow[kk + 4];
            bf16x8 bfv = pack8(lo, hi);
            *(bf16x8*)&Sout[kk] = bfv;
            #pragma unroll
            for (int mi = 0; mi < 4; ++mi) {
                int s = lr + mi*16;
                bf16x8 af = {};
                if (s < SSD) {
                    const float* sc = score + ((long)b*SSD + s)*HW + kk;
                    float4 a0 = *(const float4*)sc;
                    float4 a1 = *(const float4*)(sc + 4);
                    a0.x = __expf(a0.x); a0.y = __expf(a0.y);
                    a0.z = __expf(a0.z); a0.w = __expf(a0.w);
                    a1.x = __expf(a1.x); a1.y = __expf(a1.y);
                    a1.z = __expf(a1.z); a1.w = __expf(a1.w);
                    rsum[mi] += a0.x + a0.y + a0.z + a0.w + a1.x + a1.y + a1.z + a1.w;
                    af = pack8(a0, a1);
                }
                acc[mi] = __builtin_amdgcn_mfma_f32_16x16x32_bf16(af, bfv, acc[mi], 0, 0, 0);
            }
        }
        int c = n0 + lr;
        #pragma unroll
        for (int mi = 0; mi < 4; ++mi)
            #pragma unroll
            for (int r = 0; r < 4; ++r) {
                int m = mi*16 + lk*4 + r;
                atomicAdd(&ccp[((long)b*64 + m)*CDD + c], acc[mi][r]);
            }
        if (nt == 0 && w == 0) {   // row-sum contribution for this k-span (one block per group)
            #pragma unroll
            for (int mi = 0; mi < 4; ++mi) {
                float v = rsum[mi];
                v += __shfl_down(v, 16);
                v += __shfl_down(v, 32);
                int s = lr + mi*16;
                if (lk == 0 && s < SSD) atomicAdd(&sums[b*64 + s], v);
            }
        }
        return;
    }
    long gid = (long)(bid - CCBLK) * 256 + threadIdx.x;
    if (gid < (long)NBATCH*HW) {   // attn per-pixel softmax -> normalized bf16, 64 rows
        int b = (int)(gid / HW), n = (int)(gid % HW);
        const float* sp = score + (long)b*SSD*HW + n;
        float v[SSD];
        float m = -1e30f;
        #pragma unroll
        for (int s = 0; s < SSD; ++s) { v[s] = sp[(long)s*HW]; m = fmaxf(m, v[s]); }
        float sum = 0.f;
        #pragma unroll
        for (int s = 0; s < SSD; ++s) { v[s] = __expf(v[s] - m); sum += v[s]; }
        float inv = 1.f / sum;
        ushort_t* ap = attnb + (long)b*64*HW + n;
        #pragma unroll
        for (int s = 0; s < SSD; ++s) ap[(long)s*HW] = f2bf(v[s] * inv);
        #pragma unroll
        for (int s = SSD; s < 64; ++s) ap[(long)s*HW] = 0;
        return;
    }
    gid -= (long)NBATCH*HW;
    if (gid < 524288) {            // region_f copy (float4) + bf16 shadow
        long row = gid / 256, col = gid % 256;
        float4 v = reinterpret_cast<const float4*>(rf)[gid];
        reinterpret_cast<float4*>(out_region)[row*320 + col] = v;
        union { ushort_t u[4]; uint2 q; } pk;
        pk.u[0]=f2bf(v.x); pk.u[1]=f2bf(v.y); pk.u[2]=f2bf(v.z); pk.u[3]=f2bf(v.w);
        reinterpret_cast<uint2*>(rfb)[gid] = pk.q;
        return;
    }
    gid -= 524288;
    if (gid < 131072) {            // Aseg k<512: bf16 WsegT, 4 batch copies, zero-pad o>=54
        int b = (int)(gid >> 15);
        int r = (int)(gid & 32767);
        int o = r >> 9, k = r & 511;
        asegb[(long)b*36864 + (long)o*576 + k] = f2bf(o < SSD ? W_seg[k*SSD + o] : 0.f);
        return;
    }
    gid -= 131072;
    if (gid < BT_TOTAL) {
        int i = (int)gid;
        float v;
        if (i < BT_SIN)        { int j=i;            int n=j>>10, k=j&1023; v = W_rin[k*256+n]; }
        else if (i < BT_HEADS) { int j=i-BT_SIN;     int n=j>>9,  k=j&511;  v = W_sin[k*256+n]; }
        else if (i < BT_GOUT)  { int j=i-BT_HEADS;   int h=j>>14, r=j&16383; int f=r>>8, k=r&255;
                                 v = W_heads[(h*256+k)*64+f]; }
        else if (i < BT_ROUT)  { int j=i-BT_GOUT;    int n=j>>8,  k=j&255;  v = W_gout[k*256+n]; }
        else if (i < BT_SOUT)  { int j=i-BT_ROUT;    int n=j>>8,  k=j&255;  v = W_rout[k*256+n]; }
        else if (i < BT_SEG2)  { int j=i-BT_SOUT;    int n=j>>8,  k=j&255;  v = W_sout[k*128+n]; }
        else                   { int j=i-BT_SEG2;    int o=j>>7,  k=j&127;
                                 v = (o < SSD) ? W_seg[(512+k)*SSD + o] : 0.f; }
        bt[i] = f2bf(v);
        return;
    }
    gid -= BT_TOTAL;
    if (gid < 16384) {             // Wcomb^T[od][k] = sum_o W_sout[k,o] * Wseg2[o,od]
        int od = (int)(gid >> 8), k = (int)(gid & 255);
        float v = 0.f;
        if (od < SSD)
            for (int o = 0; o < 128; ++o)
                v += W_sout[k*128 + o] * W_seg[(512+o)*SSD + od];
        wcomb[(long)od*256 + k] = f2bf(v);
        return;
    }
    gid -= 16384;
    if (gid < 64) {                // bias2[od] = sum_o b_sout[o] * Wseg2[o,od]
        int od = (int)gid;
        float v = 0.f;
        if (od < SSD)
            for (int o = 0; o < 128; ++o)
                v += b_sout[o] * W_seg[(512+o)*SSD + od];
        bias2[od] = v;
    }
}

// ---------------- seg K-split bodies ----------------
// seg512: K=0..512 (stuffb), writes segb = acc + bias (fp32)
__device__ __forceinline__
void seg512_body(int nt, int b,
                 const ushort_t* __restrict__ stuffb,
                 const ushort_t* __restrict__ asegb, const float* __restrict__ b_seg,
                 float* __restrict__ seg)
{
    int w = threadIdx.x >> 6, l = threadIdx.x & 63;
    int lr = l & 15, lk = l >> 4;
    int n0 = nt*128 + w*32;
    const ushort_t* A = asegb + (long)b*36864;
    const ushort_t* S = stuffb + (long)b*CDD*HW;
    f32x4 acc[4][2] = {};
    int n1 = min(n0 + lr, HW-1);
    int n2 = min(n0 + 16 + lr, HW-1);

    for (int k0 = 0; k0 < 512; k0 += 32) {
        const ushort_t* Bsrc = S + (long)k0*HW;
        long kb = (long)(lk*8)*HW;
        union { bf16x8 v; ushort_t u[8]; } b0, b1;
        #pragma unroll
        for (int u = 0; u < 8; ++u) {
            b0.u[u] = Bsrc[kb + (long)u*HW + n1];
            b1.u[u] = Bsrc[kb + (long)u*HW + n2];
        }
        #pragma unroll
        for (int ot = 0; ot < 4; ++ot) {
            bf16x8 af = *(const bf16x8*)&A[(ot*16 + lr)*576 + k0 + lk*8];
            acc[ot][0] = __builtin_amdgcn_mfma_f32_16x16x32_bf16(af, b0.v, acc[ot][0], 0,0,0);
            acc[ot][1] = __builtin_amdgcn_mfma_f32_16x16x32_bf16(af, b1.v, acc[ot][1], 0,0,0);
        }
    }

    #pragma unroll
    for (int ot = 0; ot < 4; ++ot) {
        #pragma unroll
        for (int r = 0; r < 4; ++r) {
            int o = ot*16 + lk*4 + r;
            if (o >= SSD) continue;
            float bb = b_seg[o];
            int na = n0 + lr, nb = n0 + 16 + lr;
            if (na < HW) seg[((long)b*SSD + o)*HW + na] = acc[ot][0][r] + bb;
            if (nb < HW) seg[((long)b*SSD + o)*HW + nb] = acc[ot][1][r] + bb;
        }
    }
}

// segk64: K=512..576 (attnb x M2), accumulates segb += acc
__device__ __forceinline__
void segk64_body(int nt, int b,
                 const ushort_t* __restrict__ attnb,
                 const ushort_t* __restrict__ asegb,
                 float* __restrict__ seg)
{
    int w = threadIdx.x >> 6, l = threadIdx.x & 63;
    int lr = l & 15, lk = l >> 4;
    int n0 = nt*128 + w*32;
    const ushort_t* A = asegb + (long)b*36864;
    const ushort_t* T = attnb + (long)b*64*HW;
    f32x4 acc[4][2] = {};
    int n1 = min(n0 + lr, HW-1);
    int n2 = min(n0 + 16 + lr, HW-1);

    #pragma unroll
    for (int k0 = 512; k0 < 576; k0 += 32) {
        const ushort_t* Bsrc = T + (long)(k0-512)*HW;
        long kb = (long)(lk*8)*HW;
        union { bf16x8 v; ushort_t u[8]; } b0, b1;
        #pragma unroll
        for (int u = 0; u < 8; ++u) {
            b0.u[u] = Bsrc[kb + (long)u*HW + n1];
            b1.u[u] = Bsrc[kb + (long)u*HW + n2];
        }
        #pragma unroll
        for (int ot = 0; ot < 4; ++ot) {
            bf16x8 af = *(const bf16x8*)&A[(ot*16 + lr)*576 + k0 + lk*8];
            acc[ot][0] = __builtin_amdgcn_mfma_f32_16x16x32_bf16(af, b0.v, acc[ot][0], 0,0,0);
            acc[ot][1] = __builtin_amdgcn_mfma_f32_16x16x32_bf16(af, b1.v, acc[ot][1], 0,0,0);
        }
    }

    #pragma unroll
    for (int ot = 0; ot < 4; ++ot) {
        #pragma unroll
        for (int r = 0; r < 4; ++r) {
            int o = ot*16 + lk*4 + r;
            if (o >= SSD) continue;
            int na = n0 + lr, nb = n0 + 16 + lr;
            if (na < HW) { long i = ((long)b*SSD + o)*HW + na; seg[i] += acc[ot][0][r]; }
            if (nb < HW) { long i = ((long)b*SSD + o)*HW + nb; seg[i] += acc[ot][1][r]; }
        }
    }
}

// ---------------- barrier-free MFMA GEMM body ----------------
template<bool AF32, int OUTMODE>
__device__ __forceinline__
void mm_body(int bx, int by, int bz,
             const void* __restrict__ Ap, const ushort_t* __restrict__ Bt,
             void* __restrict__ Cp, const float* __restrict__ bias,
             int M, int N, int K, int lda, int ldc,
             long sA, int zdivA, long sB, int zmodB, long sC)
{
    int z = bz;
    int w = threadIdx.x >> 6, l = threadIdx.x & 63;
    int lr = l & 15, lk = l >> 4;
    int m0 = bx * 64 + w * 16;
    int n0 = by * 64;
    const ushort_t* bt = Bt + (long)(z % zmodB) * sB;
    int mload = min(m0 + lr, M - 1);
    const float*    Af = (const float*)Ap    + (long)(z / zdivA) * sA + (long)mload * lda;
    const ushort_t* Ab = (const ushort_t*)Ap + (long)(z / zdivA) * sA + (long)mload * lda;
    f32x4 acc[4] = {};

    #pragma unroll 2
    for (int k0 = 0; k0 < K; k0 += 32) {
        int kk = k0 + lk * 8;
        bf16x8 af;
        if (AF32) {
            float4 lo = *(const float4*)&Af[kk];
            float4 hi = *(const float4*)&Af[kk + 4];
            af = pack8(lo, hi);
        } else {
            af = *(const bf16x8*)&Ab[kk];
        }
        #pragma unroll
        for (int j = 0; j < 4; ++j) {
            bf16x8 bf = *(const bf16x8*)&bt[(long)(n0 + j*16 + lr) * K + kk];
            acc[j] = __builtin_amdgcn_mfma_f32_16x16x32_bf16(af, bf, acc[j], 0, 0, 0);
        }
    }

    #pragma unroll
    for (int j = 0; j < 4; ++j) {
        int n = n0 + j*16 + lr;
        float bb = bias ? bias[n] : 0.f;
        #pragma unroll
        for (int r = 0; r < 4; ++r) {
            int m = m0 + lk*4 + r;
            if (OUTMODE == 2) {
                float v = acc[j][r] + bb;
                ((ushort_t*)Cp)[(long)z * sC + (long)n * ldc + m] =
                    (m < M) ? f2bf(v) : (ushort_t)0;
            } else {
                if (m >= M) continue;
                float v = acc[j][r] + bb;
                if (OUTMODE == 0)
                    ((float*)Cp)[(long)z * sC + (long)m * ldc + n] = v;
                else
                    ((ushort_t*)Cp)[(long)z * sC + (long)m * ldc + n] = f2bf(v);
            }
        }
    }
}

// ---------------- nodes (144) + seg512 fillers (80, sid 0..79) ----------------
__global__ __launch_bounds__(256)
void nodes_seg(const ushort_t* __restrict__ rfb, const ushort_t* __restrict__ btRin,
               const float* __restrict__ ccp, const float* __restrict__ sums,
               const ushort_t* __restrict__ btSin, ushort_t* __restrict__ nodes,
               const float* __restrict__ b_rin, const float* __restrict__ b_sin,
               const ushort_t* __restrict__ stuffb, const ushort_t* __restrict__ asegb,
               const float* __restrict__ b_seg, float* __restrict__ segb)
{
    int bid = blockIdx.x;
    if (bid >= 144) {
        int sid = bid - 144;                    // 0..79
        seg512_body(sid % 119, sid / 119, stuffb, asegb, b_seg, segb);
        return;
    }
    int bx = bid % 9, by = (bid/9) % 4, bz = bid / 36;
    if (bx < 8) {
        mm_body<false, 1>(bx, by, bz, rfb, btRin, nodes, b_rin,
                          512, 256, 1024, 1024, 256, 512L*1024, 1, 0, 1, (long)NNODE*CGD);
        return;
    }
    int w = threadIdx.x >> 6, l = threadIdx.x & 63;
    int lr = l & 15, lk = l >> 4;
    int m0 = w * 16, n0 = by * 64;
    int mload = min(m0 + lr, SSD - 1);
    const float* Af = ccp + ((long)bz*64 + mload)*CDD;
    float inv = 1.f / sums[bz*64 + mload];
    f32x4 acc[4] = {};

    #pragma unroll 2
    for (int k0 = 0; k0 < CDD; k0 += 32) {
        int kk = k0 + lk * 8;
        float4 lo = *(const float4*)&Af[kk];
        float4 hi = *(const float4*)&Af[kk + 4];
        lo.x *= inv; lo.y *= inv; lo.z *= inv; lo.w *= inv;
        hi.x *= inv; hi.y *= inv; hi.z *= inv; hi.w *= inv;
        bf16x8 af = pack8(lo, hi);
        #pragma unroll
        for (int j = 0; j < 4; ++j) {
            bf16x8 bf = *(const bf16x8*)&btSin[(long)(n0 + j*16 + lr) * CDD + kk];
            acc[j] = __builtin_amdgcn_mfma_f32_16x16x32_bf16(af, bf, acc[j], 0, 0, 0);
        }
    }

    #pragma unroll
    for (int j = 0; j < 4; ++j) {
        int n = n0 + j*16 + lr;
        float bb = b_sin[n];
        #pragma unroll
        for (int r = 0; r < 4; ++r) {
            int m = m0 + lk*4 + r;
            if (m >= SSD) continue;
            nodes[(long)bz*NNODE*CGD + (long)(512 + m)*CGD + n] = f2bf(acc[j][r] + bb);
        }
    }
}

// ---------------- WhT heads + s1/s2 (144) + seg512 fillers (80, sid 80..159) ----------------
__global__ __launch_bounds__(256)
void wht_seg(const ushort_t* __restrict__ nodes, const ushort_t* __restrict__ btHeads,
             ushort_t* __restrict__ wht, const float* __restrict__ a_heads,
             float* __restrict__ s1, float* __restrict__ s2,
             const ushort_t* __restrict__ stuffb, const ushort_t* __restrict__ asegb,
             const float* __restrict__ b_seg, float* __restrict__ segb)
{
    int bid = blockIdx.x;
    if (bid >= 144) {
        int sid = bid - 144 + 80;
        seg512_body(sid % 119, sid / 119, stuffb, asegb, b_seg, segb);
        return;
    }
    int bx = bid % 9, z = bid / 9;                // z = b*4 + h
    int w = threadIdx.x >> 6, l = threadIdx.x & 63;
    int lr = l & 15, lk = l >> 4;
    int m0 = bx*64 + w*16;
    const ushort_t* bt = btHeads + (long)(z & 3) * (64L*256);
    int mload = min(m0 + lr, NNODE - 1);
    const ushort_t* Ab = nodes + (long)(z >> 2)*((long)NNODE*CGD) + (long)mload*CGD;
    f32x4 acc[4] = {};

    #pragma unroll 2
    for (int k0 = 0; k0 < 256; k0 += 32) {
        int kk = k0 + lk*8;
        bf16x8 af = *(const bf16x8*)&Ab[kk];
        #pragma unroll
        for (int j = 0; j < 4; ++j) {
            bf16x8 bf = *(const bf16x8*)&bt[(long)(j*16 + lr)*256 + kk];
            acc[j] = __builtin_amdgcn_mfma_f32_16x16x32_bf16(af, bf, acc[j], 0, 0, 0);
        }
    }

    const float* av = a_heads + (long)(z & 3)*128;
    ushort_t* Wout = wht + (long)z*(64L*NPAD);
    float p1[4] = {0.f,0.f,0.f,0.f}, p2[4] = {0.f,0.f,0.f,0.f};
    #pragma unroll
    for (int j = 0; j < 4; ++j) {
        int f = j*16 + lr;
        float c1 = av[f], c2 = av[64 + f];
        #pragma unroll
        for (int r = 0; r < 4; ++r) {
            int m = m0 + lk*4 + r;
            float v = acc[j][r];
            Wout[(long)f*NPAD + m] = (m < NNODE) ? f2bf(v) : (ushort_t)0;
            if (m < NNODE) { p1[r] += v*c1; p2[r] += v*c2; }
        }
    }
    #pragma unroll
    for (int r = 0; r < 4; ++r)
        #pragma unroll
        for (int off = 1; off < 16; off <<= 1) {
            p1[r] += __shfl_xor(p1[r], off);
            p2[r] += __shfl_xor(p2[r], off);
        }
    if (lr == 0) {
        #pragma unroll
        for (int r = 0; r < 4; ++r) {
            int m = m0 + lk*4 + r;
            if (m < NNODE) {
                s1[(long)z*NPAD + m] = p1[r];
                s2[(long)z*NPAD + m] = p2[r];
            }
        }
    }
}

// ---------------- MFMA attention body ----------------
template<int F, int HEADMODE>
__device__ __forceinline__
void att_body(int bx, int z, const ushort_t* __restrict__ WhTall,
              const float* __restrict__ s1v, const float* __restrict__ s2v,
              ushort_t* __restrict__ outbuf)
{
    constexpr int FT = F / 16;
    const ushort_t* W  = WhTall + (long)z * F * NPAD;
    const float* s1 = s1v + (long)z * NPAD;
    const float* s2 = s2v + (long)z * NPAD;
    int w = threadIdx.x >> 6, l = threadIdx.x & 63;
    int lr = l & 15, lk = l >> 4;

    __shared__ float s2sh[NPAD];
    __shared__ float redm[4];
    float mxl = -1e30f;
    for (int i = threadIdx.x; i < NPAD; i += 256) {
        float v = (i < NNODE) ? s2[i] : -1e30f;
        s2sh[i] = v;
        mxl = fmaxf(mxl, v);
    }
    #pragma unroll
    for (int off = 32; off >= 1; off >>= 1) mxl = fmaxf(mxl, __shfl_down(mxl, off));
    if (l == 0) redm[w] = mxl;
    __syncthreads();
    float s2max = fmaxf(fmaxf(redm[0], redm[1]), fmaxf(redm[2], redm[3]));

    int m0 = bx * 64 + w * 16;
    float s1r = s1[min(m0 + lr, NNODE - 1)];
    float mrow = lrelu04(s1r + s2max);

    union { bf16x8 v; ushort_t u[8]; } onesu;
    #pragma unroll
    for (int u = 0; u < 8; ++u) onesu.u[u] = 0x3F80;
    bf16x8 ones = onesu.v;

    f32x4 acc[FT] = {};
    f32x4 accw = {};

    for (int j0 = 0; j0 < NPAD; j0 += 32) {
        float wv[8];
        #pragma unroll
        for (int u = 0; u < 8; ++u) {
            float e = lrelu04(s1r + s2sh[j0 + lk*8 + u]);
            wv[u] = __expf(e - mrow);       // exactly 0 for padded j
        }
        float4 lo = {wv[0], wv[1], wv[2], wv[3]};
        float4 hi = {wv[4], wv[5], wv[6], wv[7]};
        bf16x8 af = pack8(lo, hi);
        accw = __builtin_amdgcn_mfma_f32_16x16x32_bf16(af, ones, accw, 0, 0, 0);
        #pragma unroll
        for (int ft = 0; ft < FT; ++ft) {
            bf16x8 bf = *(const bf16x8*)&W[(long)(ft*16 + lr)*NPAD + j0 + lk*8];
            acc[ft] = __builtin_amdgcn_mfma_f32_16x16x32_bf16(af, bf, acc[ft], 0, 0, 0);
        }
    }

    #pragma unroll
    for (int r = 0; r < 4; ++r) {
        int m = m0 + lk*4 + r;
        if (m >= NNODE) continue;
        float inv = 1.f / accw[r];
        #pragma unroll
        for (int ft = 0; ft < FT; ++ft) {
            int f = ft*16 + lr;
            float v = eluf(acc[ft][r] * inv);
            if (HEADMODE) {
                int b = z >> 2, h = z & 3;
                outbuf[((long)(b*NNODE + m))*CGD + h*64 + f] = f2bf(v);
            } else {
                outbuf[((long)(z*NNODE + m))*CGD + f] = f2bf(v);
            }
        }
    }
}

// ---------------- att64 (144) + seg512 fillers (80, sid 160..239) ----------------
__global__ __launch_bounds__(256)
void att64_seg(const ushort_t* __restrict__ wht, const float* __restrict__ s1,
               const float* __restrict__ s2, ushort_t* __restrict__ xbuf,
               const ushort_t* __restrict__ stuffb, const ushort_t* __restrict__ asegb,
               const float* __restrict__ b_seg, float* __restrict__ segb)
{
    int bid = blockIdx.x;
    if (bid >= 144) {
        int sid = bid - 144 + 160;
        seg512_body(sid % 119, sid / 119, stuffb, asegb, b_seg, segb);
        return;
    }
    att_body<64, 1>(bid % 9, bid / 9, wht, s1, s2, xbuf);
}

// ---------------- WhT2 + s1b/s2b (144) + seg512 fillers (80, sid 240..319) ----------------
__global__ __launch_bounds__(256)
void wht2_seg(const ushort_t* __restrict__ xbuf, const ushort_t* __restrict__ btGout,
              ushort_t* __restrict__ wht2, const float* __restrict__ a_gout,
              float* __restrict__ s1b, float* __restrict__ s2b,
              const ushort_t* __restrict__ stuffb, const ushort_t* __restrict__ asegb,
              const float* __restrict__ b_seg, float* __restrict__ segb)
{
    int bid = blockIdx.x;
    if (bid >= 144) {
        int sid = bid - 144 + 240;
        seg512_body(sid % 119, sid / 119, stuffb, asegb, b_seg, segb);
        return;
    }
    int bx = bid % 9, by = (bid/9) % 4, z = bid / 36;
    int w = threadIdx.x >> 6, l = threadIdx.x & 63;
    int lr = l & 15, lk = l >> 4;
    int m0 = bx*64 + w*16;
    int n0 = by*64;
    int mload = min(m0 + lr, NNODE - 1);
    const ushort_t* Ab = xbuf + (long)z*((long)NNODE*CGD) + (long)mload*CGD;
    f32x4 acc[4] = {};

    #pragma unroll 2
    for (int k0 = 0; k0 < 256; k0 += 32) {
        int kk = k0 + lk*8;
        bf16x8 af = *(const bf16x8*)&Ab[kk];
        #pragma unroll
        for (int j = 0; j < 4; ++j) {
            bf16x8 bf = *(const bf16x8*)&btGout[(long)(n0 + j*16 + lr)*256 + kk];
            acc[j] = __builtin_amdgcn_mfma_f32_16x16x32_bf16(af, bf, acc[j], 0, 0, 0);
        }
    }

    ushort_t* Wout = wht2 + (long)z*(256L*NPAD);
    float p1[4] = {0.f,0.f,0.f,0.f}, p2[4] = {0.f,0.f,0.f,0.f};
    #pragma unroll
    for (int j = 0; j < 4; ++j) {
        int f = n0 + j*16 + lr;
        float c1 = a_gout[f], c2 = a_gout[256 + f];
        #pragma unroll
        for (int r = 0; r < 4; ++r) {
            int m = m0 + lk*4 + r;
            float v = acc[j][r];
            Wout[(long)f*NPAD + m] = (m < NNODE) ? f2bf(v) : (ushort_t)0;
            if (m < NNODE) { p1[r] += v*c1; p2[r] += v*c2; }
        }
    }
    #pragma unroll
    for (int r = 0; r < 4; ++r)
        #pragma unroll
        for (int off = 1; off < 16; off <<= 1) {
            p1[r] += __shfl_xor(p1[r], off);
            p2[r] += __shfl_xor(p2[r], off);
        }
    if (lr == 0) {
        #pragma unroll
        for (int r = 0; r < 4; ++r) {
            int m = m0 + lk*4 + r;
            if (m < NNODE) {
                atomicAdd(&s1b[(long)z*NPAD + m], p1[r]);
                atomicAdd(&s2b[(long)z*NPAD + m], p2[r]);
            }
        }
    }
}

// ---------------- gout attention + M2 (36) + seg512 fillers (156, sid 320..475) ----------------
__global__ __launch_bounds__(256)
void attg_seg(const ushort_t* __restrict__ wht2, const float* __restrict__ s1v,
              const float* __restrict__ s2v, ushort_t* __restrict__ g,
              const ushort_t* __restrict__ wcomb, const float* __restrict__ bias2,
              ushort_t* __restrict__ asegm2,
              const ushort_t* __restrict__ stuffb, const ushort_t* __restrict__ asegb,
              const float* __restrict__ b_seg, float* __restrict__ segb)
{
    int bid = blockIdx.x;
    if (bid >= 36) {
        int sid = bid - 36 + 320;
        seg512_body(sid % 119, sid / 119, stuffb, asegb, b_seg, segb);
        return;
    }
    int bx = bid % 9, z = bid / 9;
    const ushort_t* W  = wht2 + (long)z * (256L*NPAD);
    const float* s1 = s1v + (long)z * NPAD;
    const float* s2 = s2v + (long)z * NPAD;
    int t = threadIdx.x;
    int w = t >> 6, l = t & 63;
    int lr = l & 15, lk = l >> 4;

    __shared__ float s2sh[NPAD];
    __shared__ float redm[4];
    __shared__ ushort_t gld[64][264];   // class-rows stage for M2 (bx==8 only)

    float mxl = -1e30f;
    for (int i = t; i < NPAD; i += 256) {
        float v = (i < NNODE) ? s2[i] : -1e30f;
        s2sh[i] = v;
        mxl = fmaxf(mxl, v);
    }
    if (bx == 8)   // rows >= 54 (nodes >= 566) never staged below
        for (int i = t; i < 10*264; i += 256) gld[54 + i/264][i%264] = 0;
    #pragma unroll
    for (int off = 32; off >= 1; off >>= 1) mxl = fmaxf(mxl, __shfl_down(mxl, off));
    if (l == 0) redm[w] = mxl;
    __syncthreads();
    float s2max = fmaxf(fmaxf(redm[0], redm[1]), fmaxf(redm[2], redm[3]));

    int m0 = bx * 64 + w * 16;
    float s1r = s1[min(m0 + lr, NNODE - 1)];
    float mrow = lrelu04(s1r + s2max);

    union { bf16x8 v; ushort_t u[8]; } onesu;
    #pragma unroll
    for (int u = 0; u < 8; ++u) onesu.u[u] = 0x3F80;
    bf16x8 ones = onesu.v;

    f32x4 acc[16] = {};
    f32x4 accw = {};

    for (int j0 = 0; j0 < NPAD; j0 += 32) {
        float wv[8];
        #pragma unroll
        for (int u = 0; u < 8; ++u) {
            float e = lrelu04(s1r + s2sh[j0 + lk*8 + u]);
            wv[u] = __expf(e - mrow);
        }
        float4 lo = {wv[0], wv[1], wv[2], wv[3]};
        float4 hi = {wv[4], wv[5], wv[6], wv[7]};
        bf16x8 af = pack8(lo, hi);
        accw = __builtin_amdgcn_mfma_f32_16x16x32_bf16(af, ones, accw, 0, 0, 0);
        #pragma unroll
        for (int ft = 0; ft < 16; ++ft) {
            bf16x8 bf = *(const bf16x8*)&W[(long)(ft*16 + lr)*NPAD + j0 + lk*8];
            acc[ft] = __builtin_amdgcn_mfma_f32_16x16x32_bf16(af, bf, acc[ft], 0, 0, 0);
        }
    }

    #pragma unroll
    for (int r = 0; r < 4; ++r) {
        int m = m0 + lk*4 + r;
        if (m >= NNODE) continue;
        float inv = 1.f / accw[r];
        #pragma unroll
        for (int ft = 0; ft < 16; ++ft) {
            int f = ft*16 + lr;
            ushort_t vb = f2bf(eluf(acc[ft][r] * inv));
            g[((long)(z*NNODE + m))*CGD + f] = vb;
            if (bx == 8) gld[m - 512][f] = vb;
        }
    }

    if (bx == 8) {  // M2^T = (g_class @ Wcomb)^T + bias2 -> Aseg[:, :, 512:576]
        __syncthreads();
        f32x4 acc2[4] = {};
        #pragma unroll 2
        for (int k0 = 0; k0 < 256; k0 += 32) {
            int kk = k0 + lk*8;
            bf16x8 af = *(const bf16x8*)&gld[w*16 + lr][kk];
            #pragma unroll
            for (int j = 0; j < 4; ++j) {
                bf16x8 bf = *(const bf16x8*)&wcomb[(long)(j*16 + lr)*256 + kk];
                acc2[j] = __builtin_amdgcn_mfma_f32_16x16x32_bf16(af, bf, acc2[j], 0, 0, 0);
            }
        }
        #pragma unroll
        for (int j = 0; j < 4; ++j) {
            int n = j*16 + lr;
            float bb = bias2[n];
            #pragma unroll
            for (int r = 0; r < 4; ++r) {
                int m = w*16 + lk*4 + r;
                asegm2[(long)z*36864 + (long)n*576 + m] =
                    (m < SSD) ? f2bf(acc2[j][r] + bb) : (ushort_t)0;
            }
        }
    }
}

// ---------------- rout GEMM (128) + segK64 accumulate (476) ----------------
__global__ __launch_bounds__(256)
void rout_segk(const ushort_t* __restrict__ g_bf, const ushort_t* __restrict__ btRout,
               float* __restrict__ outreg, const float* __restrict__ b_rout,
               const ushort_t* __restrict__ attnb, const ushort_t* __restrict__ asegb,
               float* __restrict__ segb)
{
    int bid = blockIdx.x;
    if (bid < 128) {
        int x = bid & 7, y = (bid >> 3) & 3, z = bid >> 5;
        mm_body<false, 0>(x, y, z, g_bf, btRout, outreg, b_rout,
                          512, 256, 256, 256, 1280, (long)NNODE*CGD, 1, 0, 1, 512L*1280);
    } else {
        int sid = bid - 128;
        segk64_body(sid % 119, sid / 119, attnb, asegb, segb);
    }
}

// ---------------- bilinear 4x upsample ----------------
__global__ __launch_bounds__(256)
void resize_v2_kernel(const float* __restrict__ seg, float* __restrict__ out)
{
    long u = (long)blockIdx.x * 256 + threadIdx.x;
    const long TOT4 = (long)NBATCH * SSD * 400 * 152;
    if (u >= TOT4) return;
    int m = (int)(u % 152);
    long r = u / 152;
    int y = (int)(r % 400);
    long c = r / 400;
    float fy = y * 0.25f - 0.375f;
    int y0 = (int)floorf(fy);
    float wy = fy - (float)y0;
    int y0c = max(y0, 0), y1c = min(y0 + 1, 99);
    const float* sp = seg + c * HW;
    int xm = max(m - 1, 0), xp = min(m + 1, 151);
    float r0a = sp[y0c * 152 + xm], r0b = sp[y0c * 152 + m], r0c = sp[y0c * 152 + xp];
    float r1a = sp[y1c * 152 + xm], r1b = sp[y1c * 152 + m], r1c = sp[y1c * 152 + xp];
    float ra = r0a + wy * (r1a - r0a);
    float rb = r0b + wy * (r1b - r0b);
    float rc = r0c + wy * (r1c - r0c);
    float4 o4;
    o4.x = 0.375f * ra + 0.625f * rb;
    o4.y = 0.125f * ra + 0.875f * rb;
    o4.z = 0.875f * rb + 0.125f * rc;
    o4.w = 0.625f * rb + 0.375f * rc;
    reinterpret_cast<float4*>(out)[u] = o4;
}

// ---------------- host ----------------
extern "C" void kernel_launch(void* const* d_in, const int* in_sizes, int n_in,
                              void* d_out, int out_size, void* d_ws, size_t ws_size,
                              hipStream_t stream)
{
    const float* region_f = (const float*)d_in[0];
    const float* stuff    = (const float*)d_in[1];
    const float* score    = (const float*)d_in[2];
    const float* W_rin    = (const float*)d_in[3];
    const float* b_rin    = (const float*)d_in[4];
    const float* W_sin    = (const float*)d_in[5];
    const float* b_sin    = (const float*)d_in[6];
    const float* W_heads  = (const float*)d_in[7];
    const float* a_heads  = (const float*)d_in[8];
    const float* W_gout   = (const float*)d_in[9];
    const float* a_gout   = (const float*)d_in[10];
    const float* W_rout   = (const float*)d_in[11];
    const float* b_rout   = (const float*)d_in[12];
    const float* W_sout   = (const float*)d_in[13];
    const float* b_sout   = (const float*)d_in[14];
    const float* W_seg    = (const float*)d_in[15];
    const float* b_seg    = (const float*)d_in[16];

    float* out = (float*)d_out;
    float* ws  = (float*)d_ws;

    float* ccp     = ws + OFF_CC;
    ushort_t* nodes_bf = (ushort_t*)(ws + OFF_NODES);
    ushort_t* wht  = (ushort_t*)(ws + OFF_WH);     // [16][64][576]
    float* s1      = ws + OFF_S1;
    float* s2      = ws + OFF_S2;
    ushort_t* xbuf_bf = (ushort_t*)(ws + OFF_X);
    ushort_t* wht2 = (ushort_t*)(ws + OFF_WH2);    // [4][256][576]
    float* s1b     = ws + OFF_S1B;
    float* s2b     = ws + OFF_S2B;
    ushort_t* g_bf = (ushort_t*)(ws + OFF_G);
    float* sums    = ws + OFF_SUMS;
    ushort_t* bt   = (ushort_t*)(ws + OFF_BT);
    ushort_t* asegb = (ushort_t*)(ws + OFF_ASEG);  // bf16 [4][64][576]
    float* segb    = ws + OFF_SEG;
    ushort_t* rfb  = (ushort_t*)(ws + OFF_RFB);    // bf16 region_f
    ushort_t* wcomb = (ushort_t*)(ws + OFF_WCOMB);
    float* bias2v  = ws + OFF_B2;
    ushort_t* attnb = (ushort_t*)(ws + OFF_ATTNB);

    float* out_region = out;                    // (2048,1280)
    float* out_seg    = out + 2048L*1280;       // (4,54,400,608)
    ushort_t* stuffb  = (ushort_t*)out_seg;     // bf16 scratch, dead before resize

    // 0. zero atomic accumulators (ccp, s1b/s2b, sums)
    zero_init<<<532, 256, 0, stream>>>(ccp, s1b, sums);

    // 1. class_center MFMA (NSPLIT=95 -> 3040 blocks, ~47 waves/CU; inline exp(score),
    //    atomic split-K + row sums, XCD-grouped) + all indep prep fillers
    cc_prep<<<CCBLK + 5326, 256, 0, stream>>>(stuff, stuffb, ccp, sums, score, attnb,
                                              region_f, out_region, rfb, W_seg, asegb,
                                              W_rin, W_sin, W_heads, W_gout, W_rout, W_sout,
                                              b_sout, bt, wcomb, bias2v);

    // 2. nodes (144) + seg512 fillers 0..79
    nodes_seg<<<224, 256, 0, stream>>>(
        rfb, bt + BT_RIN, ccp, sums, bt + BT_SIN, nodes_bf, b_rin, b_sin,
        stuffb, asegb, b_seg, segb);

    // 3. WhT + s1/s2 (144) + seg512 fillers 80..159
    wht_seg<<<224, 256, 0, stream>>>(
        nodes_bf, bt + BT_HEADS, wht, a_heads, s1, s2,
        stuffb, asegb, b_seg, segb);

    // 4. head attention (144) + seg512 fillers 160..239
    att64_seg<<<224, 256, 0, stream>>>(
        wht, s1, s2, xbuf_bf, stuffb, asegb, b_seg, segb);

    // 5. WhT2 + s1b/s2b (144) + seg512 fillers 240..319
    wht2_seg<<<224, 256, 0, stream>>>(
        xbuf_bf, bt + BT_GOUT, wht2, a_gout, s1b, s2b,
        stuffb, asegb, b_seg, segb);

    // 6. gout attention + M2 (36) + seg512 fillers 320..475 (hidden under straggler)
    attg_seg<<<192, 256, 0, stream>>>(
        wht2, s1b, s2b, g_bf, wcomb, bias2v, asegb + 512,
        stuffb, asegb, b_seg, segb);

    // 7. rout GEMM (128) + segK64 accumulate into segb (476)
    rout_segk<<<604, 256, 0, stream>>>(
        g_bf, bt + BT_ROUT, out_region + 1024, b_rout, attnb, asegb, segb);

    // 8. bilinear resize -> output1
    resize_v2_kernel<<<((long)NBATCH*SSD*400*152 + 255)/256, 256, 0, stream>>>(segb, out_seg);
}

// Round 13
// 270.819 us; speedup vs baseline: 1.0529x; 1.0529x over previous
//
#include <hip/hip_runtime.h>

#define HW 15200
#define SSD 54
#define NBATCH 4
#define NNODE 566
#define NPAD 576
#define CGD 256
#define CDD 512
#define NSPLIT 95
#define KSPAN 160   // 15200/95
#define NGRP (NSPLIT*NBATCH)          // 380
#define CCBLK 3072                    // ceil(380/8)*64

typedef __attribute__((ext_vector_type(4))) float f32x4;
typedef __attribute__((ext_vector_type(8))) short bf16x8;
typedef unsigned short ushort_t;

// BT sub-offsets (ushort units)
#define BT_RIN   0
#define BT_SIN   262144
#define BT_HEADS 393216
#define BT_GOUT  458752
#define BT_ROUT  524288
#define BT_SOUT  589824
#define BT_SEG2  622592
#define BT_TOTAL 630784

// ---------------- ws layout (float units) ----------------
static constexpr long OFF_P     = 0;                                    // pb bf16 [4][64][HW] (exp, unnormalized)
static constexpr long OFF_CC    = OFF_P     + (long)NBATCH*SSD*HW;      // fp32 ccp [4][64][512] (atomic acc)
static constexpr long OFF_NODES = OFF_CC    + (long)NBATCH*64*CDD;      // bf16 [4][566][256]
static constexpr long OFF_WH    = OFF_NODES + (long)NBATCH*NNODE*CGD;   // WhT bf16 [16][64][576]
static constexpr long OFF_S1    = OFF_WH    + (long)16*NNODE*64;
static constexpr long OFF_S2    = OFF_S1    + 16*NPAD;
static constexpr long OFF_X     = OFF_S2    + 16*NPAD;                  // bf16 [4][566][256]
static constexpr long OFF_WH2   = OFF_X     + (long)NBATCH*NNODE*CGD;   // WhT2 bf16 [4][256][576]
static constexpr long OFF_S1B   = OFF_WH2   + (long)NBATCH*NNODE*CGD;   // fp32 [4][576] (atomic acc)
static constexpr long OFF_S2B   = OFF_S1B   + NBATCH*NPAD;              // fp32 [4][576] (atomic acc)
static constexpr long OFF_G     = OFF_S2B   + NBATCH*NPAD;              // bf16 [4][566][256]
static constexpr long OFF_SUMS  = OFF_G     + (long)NBATCH*NNODE*CGD;   // fp32 [4][64] softmax row sums
static constexpr long OFF_BT    = OFF_SUMS  + 256;                      // bf16 transposed weights
static constexpr long OFF_ASEG  = OFF_BT    + (BT_TOTAL/2 + 8);         // bf16 Aseg [4][64][576]
static constexpr long OFF_SEG   = OFF_ASEG  + (long)NBATCH*64*576/2;    // segb fp32 [4][54][HW]
static constexpr long OFF_RFB   = OFF_SEG   + (long)NBATCH*SSD*HW;      // bf16 region_f [2048][1024]
static constexpr long OFF_WCOMB = OFF_RFB   + 1048576;                  // bf16 [64][256] W_sout@Wseg2 ^T
static constexpr long OFF_B2    = OFF_WCOMB + 8192;                     // fp32 [64] b_sout@Wseg2
static constexpr long OFF_ATTNB = OFF_B2    + 64;                       // bf16 attn [4][64][HW]

__device__ inline float lrelu04(float x){ return x >= 0.f ? x : 0.4f*x; }
__device__ inline float eluf(float x){ return x > 0.f ? x : __expf(x) - 1.f; }
__device__ inline ushort_t f2bf(float f){
    unsigned u = __float_as_uint(f);
    return (ushort_t)((u + 0x7FFFu + ((u >> 16) & 1u)) >> 16);
}
__device__ inline float bf2f(ushort_t u){ return __uint_as_float((unsigned)u << 16); }
__device__ inline bf16x8 pack8(float4 lo, float4 hi){
    union { bf16x8 v; ushort_t u[8]; } p;
    p.u[0]=f2bf(lo.x); p.u[1]=f2bf(lo.y); p.u[2]=f2bf(lo.z); p.u[3]=f2bf(lo.w);
    p.u[4]=f2bf(hi.x); p.u[5]=f2bf(hi.y); p.u[6]=f2bf(hi.z); p.u[7]=f2bf(hi.w);
    return p.v;
}

// ---------------- kernel 0: pure streaming head ----------------
// blk < 256:   P = exp(score) -> bf16 rows + fp32 row sums (plain store)
// blk >= 256:  stuff->bf16 convert, attn softmax, region copy, weight prep, zeros
#define SB_GIDS 1945600L   // 31,129,600 floats / 16 per thread
__global__ __launch_bounds__(256)
void stream_prep(const float* __restrict__ score, ushort_t* __restrict__ pb,
                 float* __restrict__ sums,
                 const float* __restrict__ stuff, ushort_t* __restrict__ stuffb,
                 ushort_t* __restrict__ attnb,
                 const float* __restrict__ rf, float* __restrict__ out_region,
                 ushort_t* __restrict__ rfb,
                 const float* __restrict__ W_seg, ushort_t* __restrict__ asegb,
                 const float* __restrict__ W_rin, const float* __restrict__ W_sin,
                 const float* __restrict__ W_heads, const float* __restrict__ W_gout,
                 const float* __restrict__ W_rout, const float* __restrict__ W_sout,
                 const float* __restrict__ b_sout,
                 ushort_t* __restrict__ bt, ushort_t* __restrict__ wcomb,
                 float* __restrict__ bias2,
                 float* __restrict__ ccp, float* __restrict__ s1s2b)
{
    int blk = blockIdx.x;
    int t = threadIdx.x;
    if (blk < 256) {
        int b = blk >> 6, s = blk & 63;
        ushort_t* prow = pb + ((long)b*64 + s)*HW;
        if (s >= SSD) {
            union { bf16x8 v; ushort_t u[8]; } z; 
            #pragma unroll
            for (int u = 0; u < 8; ++u) z.u[u] = 0;
            for (int i = t*8; i < HW; i += 2048) *(bf16x8*)&prow[i] = z.v;
            if (t == 0) sums[b*64 + s] = 1.f;
            return;
        }
        const float* row = score + ((long)b*SSD + s)*HW;
        __shared__ float red[4];
        float s_ = 0.f;
        for (int i = t*4; i < HW; i += 1024) {
            float4 x = *(const float4*)&row[i];
            x.x = __expf(x.x); x.y = __expf(x.y);
            x.z = __expf(x.z); x.w = __expf(x.w);
            s_ += x.x + x.y + x.z + x.w;
            union { ushort_t u[4]; uint2 q; } pk;
            pk.u[0]=f2bf(x.x); pk.u[1]=f2bf(x.y); pk.u[2]=f2bf(x.z); pk.u[3]=f2bf(x.w);
            *(uint2*)&prow[i] = pk.q;
        }
        #pragma unroll
        for (int off = 32; off >= 1; off >>= 1) s_ += __shfl_down(s_, off);
        if ((t & 63) == 0) red[t >> 6] = s_;
        __syncthreads();
        if (t == 0) sums[b*64 + s] = red[0] + red[1] + red[2] + red[3];
        return;
    }
    long gid = (long)(blk - 256)*256 + t;
    if (gid < SB_GIDS) {           // stuff fp32 -> stuffb bf16, fully coalesced
        long base = gid * 16;
        float4 v0 = *(const float4*)&stuff[base];
        float4 v1 = *(const float4*)&stuff[base + 4];
        float4 v2 = *(const float4*)&stuff[base + 8];
        float4 v3 = *(const float4*)&stuff[base + 12];
        *(bf16x8*)&stuffb[base]     = pack8(v0, v1);
        *(bf16x8*)&stuffb[base + 8] = pack8(v2, v3);
        return;
    }
    gid -= SB_GIDS;
    if (gid < (long)NBATCH*HW) {   // attn per-pixel softmax -> normalized bf16, 64 rows
        int b = (int)(gid / HW), n = (int)(gid % HW);
        const float* sp = score + (long)b*SSD*HW + n;
        float v[SSD];
        float m = -1e30f;
        #pragma unroll
        for (int s = 0; s < SSD; ++s) { v[s] = sp[(long)s*HW]; m = fmaxf(m, v[s]); }
        float sum = 0.f;
        #pragma unroll
        for (int s = 0; s < SSD; ++s) { v[s] = __expf(v[s] - m); sum += v[s]; }
        float inv = 1.f / sum;
        ushort_t* ap = attnb + (long)b*64*HW + n;
        #pragma unroll
        for (int s = 0; s < SSD; ++s) ap[(long)s*HW] = f2bf(v[s] * inv);
        #pragma unroll
        for (int s = SSD; s < 64; ++s) ap[(long)s*HW] = 0;
        return;
    }
    gid -= (long)NBATCH*HW;
    if (gid < 524288) {            // region_f copy (float4) + bf16 shadow
        long row = gid / 256, col = gid % 256;
        float4 v = reinterpret_cast<const float4*>(rf)[gid];
        reinterpret_cast<float4*>(out_region)[row*320 + col] = v;
        union { ushort_t u[4]; uint2 q; } pk;
        pk.u[0]=f2bf(v.x); pk.u[1]=f2bf(v.y); pk.u[2]=f2bf(v.z); pk.u[3]=f2bf(v.w);
        reinterpret_cast<uint2*>(rfb)[gid] = pk.q;
        return;
    }
    gid -= 524288;
    if (gid < 131072) {            // Aseg k<512: bf16 WsegT, 4 batch copies, zero-pad o>=54
        int b = (int)(gid >> 15);
        int r = (int)(gid & 32767);
        int o = r >> 9, k = r & 511;
        asegb[(long)b*36864 + (long)o*576 + k] = f2bf(o < SSD ? W_seg[k*SSD + o] : 0.f);
        return;
    }
    gid -= 131072;
    if (gid < BT_TOTAL) {
        int i = (int)gid;
        float v;
        if (i < BT_SIN)        { int j=i;            int n=j>>10, k=j&1023; v = W_rin[k*256+n]; }
        else if (i < BT_HEADS) { int j=i-BT_SIN;     int n=j>>9,  k=j&511;  v = W_sin[k*256+n]; }
        else if (i < BT_GOUT)  { int j=i-BT_HEADS;   int h=j>>14, r=j&16383; int f=r>>8, k=r&255;
                                 v = W_heads[(h*256+k)*64+f]; }
        else if (i < BT_ROUT)  { int j=i-BT_GOUT;    int n=j>>8,  k=j&255;  v = W_gout[k*256+n]; }
        else if (i < BT_SOUT)  { int j=i-BT_ROUT;    int n=j>>8,  k=j&255;  v = W_rout[k*256+n]; }
        else if (i < BT_SEG2)  { int j=i-BT_SOUT;    int n=j>>8,  k=j&255;  v = W_sout[k*128+n]; }
        else                   { int j=i-BT_SEG2;    int o=j>>7,  k=j&127;
                                 v = (o < SSD) ? W_seg[(512+k)*SSD + o] : 0.f; }
        bt[i] = f2bf(v);
        return;
    }
    gid -= BT_TOTAL;
    if (gid < 16384) {             // Wcomb^T[od][k] = sum_o W_sout[k,o] * Wseg2[o,od]
        int od = (int)(gid >> 8), k = (int)(gid & 255);
        float v = 0.f;
        if (od < SSD)
            for (int o = 0; o < 128; ++o)
                v += W_sout[k*128 + o] * W_seg[(512+o)*SSD + od];
        wcomb[(long)od*256 + k] = f2bf(v);
        return;
    }
    gid -= 16384;
    if (gid < 64) {                // bias2[od] = sum_o b_sout[o] * Wseg2[o,od]
        int od = (int)gid;
        float v = 0.f;
        if (od < SSD)
            for (int o = 0; o < 128; ++o)
                v += b_sout[o] * W_seg[(512+o)*SSD + od];
        bias2[od] = v;
        return;
    }
    gid -= 64;
    if (gid < 131072) { ccp[gid] = 0.f; return; }
    gid -= 131072;
    if (gid < 4608) s1s2b[gid] = 0.f;
}

// ---------------- kernel 1: pure cc GEMM (bf16 operands, atomic split-K) ----------------
// 3040 active blocks, XCD-grouped (bid%8): 8 nt-blocks sharing one P k-slice on one XCD L2.
// No stores, no exp, half the bytes of the fused version.
__global__ __launch_bounds__(256)
void cc_gemm(const ushort_t* __restrict__ pb, const ushort_t* __restrict__ stuffb,
             float* __restrict__ ccp)
{
    int bid = blockIdx.x;
    int g = (bid >> 6) * 8 + (bid & 7);    // group = (ks,b), 0..379 (+4 idle)
    if (g >= NGRP) return;
    int nt = (bid >> 3) & 7;
    int ks = g >> 2, b = g & 3;

    int w = threadIdx.x >> 6, l = threadIdx.x & 63;
    int lr = l & 15, lk = l >> 4;
    int n0 = nt*64 + w*16;
    const ushort_t* Prow = pb + ((long)b*64 + lr)*HW;
    const ushort_t* Srow = stuffb + ((long)b*CDD + n0 + lr)*HW;
    f32x4 acc[4] = {};
    int kbeg = ks * KSPAN;
    #pragma unroll
    for (int k0 = kbeg; k0 < kbeg + KSPAN; k0 += 32) {
        int kk = k0 + lk*8;
        bf16x8 sv = *(const bf16x8*)&Srow[kk];
        bf16x8 p0 = *(const bf16x8*)&Prow[kk];
        bf16x8 p1 = *(const bf16x8*)&Prow[(long)16*HW + kk];
        bf16x8 p2 = *(const bf16x8*)&Prow[(long)32*HW + kk];
        bf16x8 p3 = *(const bf16x8*)&Prow[(long)48*HW + kk];
        acc[0] = __builtin_amdgcn_mfma_f32_16x16x32_bf16(p0, sv, acc[0], 0, 0, 0);
        acc[1] = __builtin_amdgcn_mfma_f32_16x16x32_bf16(p1, sv, acc[1], 0, 0, 0);
        acc[2] = __builtin_amdgcn_mfma_f32_16x16x32_bf16(p2, sv, acc[2], 0, 0, 0);
        acc[3] = __builtin_amdgcn_mfma_f32_16x16x32_bf16(p3, sv, acc[3], 0, 0, 0);
    }
    int c = n0 + lr;
    #pragma unroll
    for (int mi = 0; mi < 4; ++mi)
        #pragma unroll
        for (int r = 0; r < 4; ++r) {
            int m = mi*16 + lk*4 + r;
            atomicAdd(&ccp[((long)b*64 + m)*CDD + c], acc[mi][r]);
        }
}

// ---------------- seg K-split bodies ----------------
__device__ __forceinline__
void seg512_body(int nt, int b,
                 const ushort_t* __restrict__ stuffb,
                 const ushort_t* __restrict__ asegb, const float* __restrict__ b_seg,
                 float* __restrict__ seg)
{
    int w = threadIdx.x >> 6, l = threadIdx.x & 63;
    int lr = l & 15, lk = l >> 4;
    int n0 = nt*128 + w*32;
    const ushort_t* A = asegb + (long)b*36864;
    const ushort_t* S = stuffb + (long)b*CDD*HW;
    f32x4 acc[4][2] = {};
    int n1 = min(n0 + lr, HW-1);
    int n2 = min(n0 + 16 + lr, HW-1);

    for (int k0 = 0; k0 < 512; k0 += 32) {
        const ushort_t* Bsrc = S + (long)k0*HW;
        long kb = (long)(lk*8)*HW;
        union { bf16x8 v; ushort_t u[8]; } b0, b1;
        #pragma unroll
        for (int u = 0; u < 8; ++u) {
            b0.u[u] = Bsrc[kb + (long)u*HW + n1];
            b1.u[u] = Bsrc[kb + (long)u*HW + n2];
        }
        #pragma unroll
        for (int ot = 0; ot < 4; ++ot) {
            bf16x8 af = *(const bf16x8*)&A[(ot*16 + lr)*576 + k0 + lk*8];
            acc[ot][0] = __builtin_amdgcn_mfma_f32_16x16x32_bf16(af, b0.v, acc[ot][0], 0,0,0);
            acc[ot][1] = __builtin_amdgcn_mfma_f32_16x16x32_bf16(af, b1.v, acc[ot][1], 0,0,0);
        }
    }

    #pragma unroll
    for (int ot = 0; ot < 4; ++ot) {
        #pragma unroll
        for (int r = 0; r < 4; ++r) {
            int o = ot*16 + lk*4 + r;
            if (o >= SSD) continue;
            float bb = b_seg[o];
            int na = n0 + lr, nb = n0 + 16 + lr;
            if (na < HW) seg[((long)b*SSD + o)*HW + na] = acc[ot][0][r] + bb;
            if (nb < HW) seg[((long)b*SSD + o)*HW + nb] = acc[ot][1][r] + bb;
        }
    }
}

__device__ __forceinline__
void segk64_body(int nt, int b,
                 const ushort_t* __restrict__ attnb,
                 const ushort_t* __restrict__ asegb,
                 float* __restrict__ seg)
{
    int w = threadIdx.x >> 6, l = threadIdx.x & 63;
    int lr = l & 15, lk = l >> 4;
    int n0 = nt*128 + w*32;
    const ushort_t* A = asegb + (long)b*36864;
    const ushort_t* T = attnb + (long)b*64*HW;
    f32x4 acc[4][2] = {};
    int n1 = min(n0 + lr, HW-1);
    int n2 = min(n0 + 16 + lr, HW-1);

    #pragma unroll
    for (int k0 = 512; k0 < 576; k0 += 32) {
        const ushort_t* Bsrc = T + (long)(k0-512)*HW;
        long kb = (long)(lk*8)*HW;
        union { bf16x8 v; ushort_t u[8]; } b0, b1;
        #pragma unroll
        for (int u = 0; u < 8; ++u) {
            b0.u[u] = Bsrc[kb + (long)u*HW + n1];
            b1.u[u] = Bsrc[kb + (long)u*HW + n2];
        }
        #pragma unroll
        for (int ot = 0; ot < 4; ++ot) {
            bf16x8 af = *(const bf16x8*)&A[(ot*16 + lr)*576 + k0 + lk*8];
            acc[ot][0] = __builtin_amdgcn_mfma_f32_16x16x32_bf16(af, b0.v, acc[ot][0], 0,0,0);
            acc[ot][1] = __builtin_amdgcn_mfma_f32_16x16x32_bf16(af, b1.v, acc[ot][1], 0,0,0);
        }
    }

    #pragma unroll
    for (int ot = 0; ot < 4; ++ot) {
        #pragma unroll
        for (int r = 0; r < 4; ++r) {
            int o = ot*16 + lk*4 + r;
            if (o >= SSD) continue;
            int na = n0 + lr, nb = n0 + 16 + lr;
            if (na < HW) { long i = ((long)b*SSD + o)*HW + na; seg[i] += acc[ot][0][r]; }
            if (nb < HW) { long i = ((long)b*SSD + o)*HW + nb; seg[i] += acc[ot][1][r]; }
        }
    }
}

// ---------------- barrier-free MFMA GEMM body ----------------
template<bool AF32, int OUTMODE>
__device__ __forceinline__
void mm_body(int bx, int by, int bz,
             const void* __restrict__ Ap, const ushort_t* __restrict__ Bt,
             void* __restrict__ Cp, const float* __restrict__ bias,
             int M, int N, int K, int lda, int ldc,
             long sA, int zdivA, long sB, int zmodB, long sC)
{
    int z = bz;
    int w = threadIdx.x >> 6, l = threadIdx.x & 63;
    int lr = l & 15, lk = l >> 4;
    int m0 = bx * 64 + w * 16;
    int n0 = by * 64;
    const ushort_t* bt = Bt + (long)(z % zmodB) * sB;
    int mload = min(m0 + lr, M - 1);
    const float*    Af = (const float*)Ap    + (long)(z / zdivA) * sA + (long)mload * lda;
    const ushort_t* Ab = (const ushort_t*)Ap + (long)(z / zdivA) * sA + (long)mload * lda;
    f32x4 acc[4] = {};

    #pragma unroll 2
    for (int k0 = 0; k0 < K; k0 += 32) {
        int kk = k0 + lk * 8;
        bf16x8 af;
        if (AF32) {
            float4 lo = *(const float4*)&Af[kk];
            float4 hi = *(const float4*)&Af[kk + 4];
            af = pack8(lo, hi);
        } else {
            af = *(const bf16x8*)&Ab[kk];
        }
        #pragma unroll
        for (int j = 0; j < 4; ++j) {
            bf16x8 bf = *(const bf16x8*)&bt[(long)(n0 + j*16 + lr) * K + kk];
            acc[j] = __builtin_amdgcn_mfma_f32_16x16x32_bf16(af, bf, acc[j], 0, 0, 0);
        }
    }

    #pragma unroll
    for (int j = 0; j < 4; ++j) {
        int n = n0 + j*16 + lr;
        float bb = bias ? bias[n] : 0.f;
        #pragma unroll
        for (int r = 0; r < 4; ++r) {
            int m = m0 + lk*4 + r;
            if (OUTMODE == 2) {
                float v = acc[j][r] + bb;
                ((ushort_t*)Cp)[(long)z * sC + (long)n * ldc + m] =
                    (m < M) ? f2bf(v) : (ushort_t)0;
            } else {
                if (m >= M) continue;
                float v = acc[j][r] + bb;
                if (OUTMODE == 0)
                    ((float*)Cp)[(long)z * sC + (long)m * ldc + n] = v;
                else
                    ((ushort_t*)Cp)[(long)z * sC + (long)m * ldc + n] = f2bf(v);
            }
        }
    }
}

// ---------------- nodes (144) + seg512 fillers (80, sid 0..79) ----------------
__global__ __launch_bounds__(256)
void nodes_seg(const ushort_t* __restrict__ rfb, const ushort_t* __restrict__ btRin,
               const float* __restrict__ ccp, const float* __restrict__ sums,
               const ushort_t* __restrict__ btSin, ushort_t* __restrict__ nodes,
               const float* __restrict__ b_rin, const float* __restrict__ b_sin,
               const ushort_t* __restrict__ stuffb, const ushort_t* __restrict__ asegb,
               const float* __restrict__ b_seg, float* __restrict__ segb)
{
    int bid = blockIdx.x;
    if (bid >= 144) {
        int sid = bid - 144;                    // 0..79
        seg512_body(sid % 119, sid / 119, stuffb, asegb, b_seg, segb);
        return;
    }
    int bx = bid % 9, by = (bid/9) % 4, bz = bid / 36;
    if (bx < 8) {
        mm_body<false, 1>(bx, by, bz, rfb, btRin, nodes, b_rin,
                          512, 256, 1024, 1024, 256, 512L*1024, 1, 0, 1, (long)NNODE*CGD);
        return;
    }
    int w = threadIdx.x >> 6, l = threadIdx.x & 63;
    int lr = l & 15, lk = l >> 4;
    int m0 = w * 16, n0 = by * 64;
    int mload = min(m0 + lr, SSD - 1);
    const float* Af = ccp + ((long)bz*64 + mload)*CDD;
    float inv = 1.f / sums[bz*64 + mload];
    f32x4 acc[4] = {};

    #pragma unroll 2
    for (int k0 = 0; k0 < CDD; k0 += 32) {
        int kk = k0 + lk * 8;
        float4 lo = *(const float4*)&Af[kk];
        float4 hi = *(const float4*)&Af[kk + 4];
        lo.x *= inv; lo.y *= inv; lo.z *= inv; lo.w *= inv;
        hi.x *= inv; hi.y *= inv; hi.z *= inv; hi.w *= inv;
        bf16x8 af = pack8(lo, hi);
        #pragma unroll
        for (int j = 0; j < 4; ++j) {
            bf16x8 bf = *(const bf16x8*)&btSin[(long)(n0 + j*16 + lr) * CDD + kk];
            acc[j] = __builtin_amdgcn_mfma_f32_16x16x32_bf16(af, bf, acc[j], 0, 0, 0);
        }
    }

    #pragma unroll
    for (int j = 0; j < 4; ++j) {
        int n = n0 + j*16 + lr;
        float bb = b_sin[n];
        #pragma unroll
        for (int r = 0; r < 4; ++r) {
            int m = m0 + lk*4 + r;
            if (m >= SSD) continue;
            nodes[(long)bz*NNODE*CGD + (long)(512 + m)*CGD + n] = f2bf(acc[j][r] + bb);
        }
    }
}

// ---------------- WhT heads + s1/s2 (144) + seg512 fillers (80, sid 80..159) ----------------
__global__ __launch_bounds__(256)
void wht_seg(const ushort_t* __restrict__ nodes, const ushort_t* __restrict__ btHeads,
             ushort_t* __restrict__ wht, const float* __restrict__ a_heads,
             float* __restrict__ s1, float* __restrict__ s2,
             const ushort_t* __restrict__ stuffb, const ushort_t* __restrict__ asegb,
             const float* __restrict__ b_seg, float* __restrict__ segb)
{
    int bid = blockIdx.x;
    if (bid >= 144) {
        int sid = bid - 144 + 80;
        seg512_body(sid % 119, sid / 119, stuffb, asegb, b_seg, segb);
        return;
    }
    int bx = bid % 9, z = bid / 9;                // z = b*4 + h
    int w = threadIdx.x >> 6, l = threadIdx.x & 63;
    int lr = l & 15, lk = l >> 4;
    int m0 = bx*64 + w*16;
    const ushort_t* bt = btHeads + (long)(z & 3) * (64L*256);
    int mload = min(m0 + lr, NNODE - 1);
    const ushort_t* Ab = nodes + (long)(z >> 2)*((long)NNODE*CGD) + (long)mload*CGD;
    f32x4 acc[4] = {};

    #pragma unroll 2
    for (int k0 = 0; k0 < 256; k0 += 32) {
        int kk = k0 + lk*8;
        bf16x8 af = *(const bf16x8*)&Ab[kk];
        #pragma unroll
        for (int j = 0; j < 4; ++j) {
            bf16x8 bf = *(const bf16x8*)&bt[(long)(j*16 + lr)*256 + kk];
            acc[j] = __builtin_amdgcn_mfma_f32_16x16x32_bf16(af, bf, acc[j], 0, 0, 0);
        }
    }

    const float* av = a_heads + (long)(z & 3)*128;
    ushort_t* Wout = wht + (long)z*(64L*NPAD);
    float p1[4] = {0.f,0.f,0.f,0.f}, p2[4] = {0.f,0.f,0.f,0.f};
    #pragma unroll
    for (int j = 0; j < 4; ++j) {
        int f = j*16 + lr;
        float c1 = av[f], c2 = av[64 + f];
        #pragma unroll
        for (int r = 0; r < 4; ++r) {
            int m = m0 + lk*4 + r;
            float v = acc[j][r];
            Wout[(long)f*NPAD + m] = (m < NNODE) ? f2bf(v) : (ushort_t)0;
            if (m < NNODE) { p1[r] += v*c1; p2[r] += v*c2; }
        }
    }
    #pragma unroll
    for (int r = 0; r < 4; ++r)
        #pragma unroll
        for (int off = 1; off < 16; off <<= 1) {
            p1[r] += __shfl_xor(p1[r], off);
            p2[r] += __shfl_xor(p2[r], off);
        }
    if (lr == 0) {
        #pragma unroll
        for (int r = 0; r < 4; ++r) {
            int m = m0 + lk*4 + r;
            if (m < NNODE) {
                s1[(long)z*NPAD + m] = p1[r];
                s2[(long)z*NPAD + m] = p2[r];
            }
        }
    }
}

// ---------------- MFMA attention body ----------------
template<int F, int HEADMODE>
__device__ __forceinline__
void att_body(int bx, int z, const ushort_t* __restrict__ WhTall,
              const float* __restrict__ s1v, const float* __restrict__ s2v,
              ushort_t* __restrict__ outbuf)
{
    constexpr int FT = F / 16;
    const ushort_t* W  = WhTall + (long)z * F * NPAD;
    const float* s1 = s1v + (long)z * NPAD;
    const float* s2 = s2v + (long)z * NPAD;
    int w = threadIdx.x >> 6, l = threadIdx.x & 63;
    int lr = l & 15, lk = l >> 4;

    __shared__ float s2sh[NPAD];
    __shared__ float redm[4];
    float mxl = -1e30f;
    for (int i = threadIdx.x; i < NPAD; i += 256) {
        float v = (i < NNODE) ? s2[i] : -1e30f;
        s2sh[i] = v;
        mxl = fmaxf(mxl, v);
    }
    #pragma unroll
    for (int off = 32; off >= 1; off >>= 1) mxl = fmaxf(mxl, __shfl_down(mxl, off));
    if (l == 0) redm[w] = mxl;
    __syncthreads();
    float s2max = fmaxf(fmaxf(redm[0], redm[1]), fmaxf(redm[2], redm[3]));

    int m0 = bx * 64 + w * 16;
    float s1r = s1[min(m0 + lr, NNODE - 1)];
    float mrow = lrelu04(s1r + s2max);

    union { bf16x8 v; ushort_t u[8]; } onesu;
    #pragma unroll
    for (int u = 0; u < 8; ++u) onesu.u[u] = 0x3F80;
    bf16x8 ones = onesu.v;

    f32x4 acc[FT] = {};
    f32x4 accw = {};

    for (int j0 = 0; j0 < NPAD; j0 += 32) {
        float wv[8];
        #pragma unroll
        for (int u = 0; u < 8; ++u) {
            float e = lrelu04(s1r + s2sh[j0 + lk*8 + u]);
            wv[u] = __expf(e - mrow);       // exactly 0 for padded j
        }
        float4 lo = {wv[0], wv[1], wv[2], wv[3]};
        float4 hi = {wv[4], wv[5], wv[6], wv[7]};
        bf16x8 af = pack8(lo, hi);
        accw = __builtin_amdgcn_mfma_f32_16x16x32_bf16(af, ones, accw, 0, 0, 0);
        #pragma unroll
        for (int ft = 0; ft < FT; ++ft) {
            bf16x8 bf = *(const bf16x8*)&W[(long)(ft*16 + lr)*NPAD + j0 + lk*8];
            acc[ft] = __builtin_amdgcn_mfma_f32_16x16x32_bf16(af, bf, acc[ft], 0, 0, 0);
        }
    }

    #pragma unroll
    for (int r = 0; r < 4; ++r) {
        int m = m0 + lk*4 + r;
        if (m >= NNODE) continue;
        float inv = 1.f / accw[r];
        #pragma unroll
        for (int ft = 0; ft < FT; ++ft) {
            int f = ft*16 + lr;
            float v = eluf(acc[ft][r] * inv);
            if (HEADMODE) {
                int b = z >> 2, h = z & 3;
                outbuf[((long)(b*NNODE + m))*CGD + h*64 + f] = f2bf(v);
            } else {
                outbuf[((long)(z*NNODE + m))*CGD + f] = f2bf(v);
            }
        }
    }
}

// ---------------- att64 (144) + seg512 fillers (80, sid 160..239) ----------------
__global__ __launch_bounds__(256)
void att64_seg(const ushort_t* __restrict__ wht, const float* __restrict__ s1,
               const float* __restrict__ s2, ushort_t* __restrict__ xbuf,
               const ushort_t* __restrict__ stuffb, const ushort_t* __restrict__ asegb,
               const float* __restrict__ b_seg, float* __restrict__ segb)
{
    int bid = blockIdx.x;
    if (bid >= 144) {
        int sid = bid - 144 + 160;
        seg512_body(sid % 119, sid / 119, stuffb, asegb, b_seg, segb);
        return;
    }
    att_body<64, 1>(bid % 9, bid / 9, wht, s1, s2, xbuf);
}

// ---------------- WhT2 + s1b/s2b (144) + seg512 fillers (80, sid 240..319) ----------------
__global__ __launch_bounds__(256)
void wht2_seg(const ushort_t* __restrict__ xbuf, const ushort_t* __restrict__ btGout,
              ushort_t* __restrict__ wht2, const float* __restrict__ a_gout,
              float* __restrict__ s1b, float* __restrict__ s2b,
              const ushort_t* __restrict__ stuffb, const ushort_t* __restrict__ asegb,
              const float* __restrict__ b_seg, float* __restrict__ segb)
{
    int bid = blockIdx.x;
    if (bid >= 144) {
        int sid = bid - 144 + 240;
        seg512_body(sid % 119, sid / 119, stuffb, asegb, b_seg, segb);
        return;
    }
    int bx = bid % 9, by = (bid/9) % 4, z = bid / 36;
    int w = threadIdx.x >> 6, l = threadIdx.x & 63;
    int lr = l & 15, lk = l >> 4;
    int m0 = bx*64 + w*16;
    int n0 = by*64;
    int mload = min(m0 + lr, NNODE - 1);
    const ushort_t* Ab = xbuf + (long)z*((long)NNODE*CGD) + (long)mload*CGD;
    f32x4 acc[4] = {};

    #pragma unroll 2
    for (int k0 = 0; k0 < 256; k0 += 32) {
        int kk = k0 + lk*8;
        bf16x8 af = *(const bf16x8*)&Ab[kk];
        #pragma unroll
        for (int j = 0; j < 4; ++j) {
            bf16x8 bf = *(const bf16x8*)&btGout[(long)(n0 + j*16 + lr)*256 + kk];
            acc[j] = __builtin_amdgcn_mfma_f32_16x16x32_bf16(af, bf, acc[j], 0, 0, 0);
        }
    }

    ushort_t* Wout = wht2 + (long)z*(256L*NPAD);
    float p1[4] = {0.f,0.f,0.f,0.f}, p2[4] = {0.f,0.f,0.f,0.f};
    #pragma unroll
    for (int j = 0; j < 4; ++j) {
        int f = n0 + j*16 + lr;
        float c1 = a_gout[f], c2 = a_gout[256 + f];
        #pragma unroll
        for (int r = 0; r < 4; ++r) {
            int m = m0 + lk*4 + r;
            float v = acc[j][r];
            Wout[(long)f*NPAD + m] = (m < NNODE) ? f2bf(v) : (ushort_t)0;
            if (m < NNODE) { p1[r] += v*c1; p2[r] += v*c2; }
        }
    }
    #pragma unroll
    for (int r = 0; r < 4; ++r)
        #pragma unroll
        for (int off = 1; off < 16; off <<= 1) {
            p1[r] += __shfl_xor(p1[r], off);
            p2[r] += __shfl_xor(p2[r], off);
        }
    if (lr == 0) {
        #pragma unroll
        for (int r = 0; r < 4; ++r) {
            int m = m0 + lk*4 + r;
            if (m < NNODE) {
                atomicAdd(&s1b[(long)z*NPAD + m], p1[r]);
                atomicAdd(&s2b[(long)z*NPAD + m], p2[r]);
            }
        }
    }
}

// ---------------- gout attention + M2 (36) + seg512 fillers (156, sid 320..475) ----------------
__global__ __launch_bounds__(256)
void attg_seg(const ushort_t* __restrict__ wht2, const float* __restrict__ s1v,
              const float* __restrict__ s2v, ushort_t* __restrict__ g,
              const ushort_t* __restrict__ wcomb, const float* __restrict__ bias2,
              ushort_t* __restrict__ asegm2,
              const ushort_t* __restrict__ stuffb, const ushort_t* __restrict__ asegb,
              const float* __restrict__ b_seg, float* __restrict__ segb)
{
    int bid = blockIdx.x;
    if (bid >= 36) {
        int sid = bid - 36 + 320;
        seg512_body(sid % 119, sid / 119, stuffb, asegb, b_seg, segb);
        return;
    }
    int bx = bid % 9, z = bid / 9;
    const ushort_t* W  = wht2 + (long)z * (256L*NPAD);
    const float* s1 = s1v + (long)z * NPAD;
    const float* s2 = s2v + (long)z * NPAD;
    int t = threadIdx.x;
    int w = t >> 6, l = t & 63;
    int lr = l & 15, lk = l >> 4;

    __shared__ float s2sh[NPAD];
    __shared__ float redm[4];
    __shared__ ushort_t gld[64][264];   // class-rows stage for M2 (bx==8 only)

    float mxl = -1e30f;
    for (int i = t; i < NPAD; i += 256) {
        float v = (i < NNODE) ? s2[i] : -1e30f;
        s2sh[i] = v;
        mxl = fmaxf(mxl, v);
    }
    if (bx == 8)   // rows >= 54 (nodes >= 566) never staged below
        for (int i = t; i < 10*264; i += 256) gld[54 + i/264][i%264] = 0;
    #pragma unroll
    for (int off = 32; off >= 1; off >>= 1) mxl = fmaxf(mxl, __shfl_down(mxl, off));
    if (l == 0) redm[w] = mxl;
    __syncthreads();
    float s2max = fmaxf(fmaxf(redm[0], redm[1]), fmaxf(redm[2], redm[3]));

    int m0 = bx * 64 + w * 16;
    float s1r = s1[min(m0 + lr, NNODE - 1)];
    float mrow = lrelu04(s1r + s2max);

    union { bf16x8 v; ushort_t u[8]; } onesu;
    #pragma unroll
    for (int u = 0; u < 8; ++u) onesu.u[u] = 0x3F80;
    bf16x8 ones = onesu.v;

    f32x4 acc[16] = {};
    f32x4 accw = {};

    for (int j0 = 0; j0 < NPAD; j0 += 32) {
        float wv[8];
        #pragma unroll
        for (int u = 0; u < 8; ++u) {
            float e = lrelu04(s1r + s2sh[j0 + lk*8 + u]);
            wv[u] = __expf(e - mrow);
        }
        float4 lo = {wv[0], wv[1], wv[2], wv[3]};
        float4 hi = {wv[4], wv[5], wv[6], wv[7]};
        bf16x8 af = pack8(lo, hi);
        accw = __builtin_amdgcn_mfma_f32_16x16x32_bf16(af, ones, accw, 0, 0, 0);
        #pragma unroll
        for (int ft = 0; ft < 16; ++ft) {
            bf16x8 bf = *(const bf16x8*)&W[(long)(ft*16 + lr)*NPAD + j0 + lk*8];
            acc[ft] = __builtin_amdgcn_mfma_f32_16x16x32_bf16(af, bf, acc[ft], 0, 0, 0);
        }
    }

    #pragma unroll
    for (int r = 0; r < 4; ++r) {
        int m = m0 + lk*4 + r;
        if (m >= NNODE) continue;
        float inv = 1.f / accw[r];
        #pragma unroll
        for (int ft = 0; ft < 16; ++ft) {
            int f = ft*16 + lr;
            ushort_t vb = f2bf(eluf(acc[ft][r] * inv));
            g[((long)(z*NNODE + m))*CGD + f] = vb;
            if (bx == 8) gld[m - 512][f] = vb;
        }
    }

    if (bx == 8) {  // M2^T = (g_class @ Wcomb)^T + bias2 -> Aseg[:, :, 512:576]
        __syncthreads();
        f32x4 acc2[4] = {};
        #pragma unroll 2
        for (int k0 = 0; k0 < 256; k0 += 32) {
            int kk = k0 + lk*8;
            bf16x8 af = *(const bf16x8*)&gld[w*16 + lr][kk];
            #pragma unroll
            for (int j = 0; j < 4; ++j) {
                bf16x8 bf = *(const bf16x8*)&wcomb[(long)(j*16 + lr)*256 + kk];
                acc2[j] = __builtin_amdgcn_mfma_f32_16x16x32_bf16(af, bf, acc2[j], 0, 0, 0);
            }
        }
        #pragma unroll
        for (int j = 0; j < 4; ++j) {
            int n = j*16 + lr;
            float bb = bias2[n];
            #pragma unroll
            for (int r = 0; r < 4; ++r) {
                int m = w*16 + lk*4 + r;
                asegm2[(long)z*36864 + (long)n*576 + m] =
                    (m < SSD) ? f2bf(acc2[j][r] + bb) : (ushort_t)0;
            }
        }
    }
}

// ---------------- rout GEMM (128) + segK64 accumulate (476) ----------------
__global__ __launch_bounds__(256)
void rout_segk(const ushort_t* __restrict__ g_bf, const ushort_t* __restrict__ btRout,
               float* __restrict__ outreg, const float* __restrict__ b_rout,
               const ushort_t* __restrict__ attnb, const ushort_t* __restrict__ asegb,
               float* __restrict__ segb)
{
    int bid = blockIdx.x;
    if (bid < 128) {
        int x = bid & 7, y = (bid >> 3) & 3, z = bid >> 5;
        mm_body<false, 0>(x, y, z, g_bf, btRout, outreg, b_rout,
                          512, 256, 256, 256, 1280, (long)NNODE*CGD, 1, 0, 1, 512L*1280);
    } else {
        int sid = bid - 128;
        segk64_body(sid % 119, sid / 119, attnb, asegb, segb);
    }
}

// ---------------- bilinear 4x upsample ----------------
__global__ __launch_bounds__(256)
void resize_v2_kernel(const float* __restrict__ seg, float* __restrict__ out)
{
    long u = (long)blockIdx.x * 256 + threadIdx.x;
    const long TOT4 = (long)NBATCH * SSD * 400 * 152;
    if (u >= TOT4) return;
    int m = (int)(u % 152);
    long r = u / 152;
    int y = (int)(r % 400);
    long c = r / 400;
    float fy = y * 0.25f - 0.375f;
    int y0 = (int)floorf(fy);
    float wy = fy - (float)y0;
    int y0c = max(y0, 0), y1c = min(y0 + 1, 99);
    const float* sp = seg + c * HW;
    int xm = max(m - 1, 0), xp = min(m + 1, 151);
    float r0a = sp[y0c * 152 + xm], r0b = sp[y0c * 152 + m], r0c = sp[y0c * 152 + xp];
    float r1a = sp[y1c * 152 + xm], r1b = sp[y1c * 152 + m], r1c = sp[y1c * 152 + xp];
    float ra = r0a + wy * (r1a - r0a);
    float rb = r0b + wy * (r1b - r0b);
    float rc = r0c + wy * (r1c - r0c);
    float4 o4;
    o4.x = 0.375f * ra + 0.625f * rb;
    o4.y = 0.125f * ra + 0.875f * rb;
    o4.z = 0.875f * rb + 0.125f * rc;
    o4.w = 0.625f * rb + 0.375f * rc;
    reinterpret_cast<float4*>(out)[u] = o4;
}

// ---------------- host ----------------
extern "C" void kernel_launch(void* const* d_in, const int* in_sizes, int n_in,
                              void* d_out, int out_size, void* d_ws, size_t ws_size,
                              hipStream_t stream)
{
    const float* region_f = (const float*)d_in[0];
    const float* stuff    = (const float*)d_in[1];
    const float* score    = (const float*)d_in[2];
    const float* W_rin    = (const float*)d_in[3];
    const float* b_rin    = (const float*)d_in[4];
    const float* W_sin    = (const float*)d_in[5];
    const float* b_sin    = (const float*)d_in[6];
    const float* W_heads  = (const float*)d_in[7];
    const float* a_heads  = (const float*)d_in[8];
    const float* W_gout   = (const float*)d_in[9];
    const float* a_gout   = (const float*)d_in[10];
    const float* W_rout   = (const float*)d_in[11];
    const float* b_rout   = (const float*)d_in[12];
    const float* W_sout   = (const float*)d_in[13];
    const float* b_sout   = (const float*)d_in[14];
    const float* W_seg    = (const float*)d_in[15];
    const float* b_seg    = (const float*)d_in[16];

    float* out = (float*)d_out;
    float* ws  = (float*)d_ws;

    ushort_t* pb   = (ushort_t*)(ws + OFF_P);
    float* ccp     = ws + OFF_CC;
    ushort_t* nodes_bf = (ushort_t*)(ws + OFF_NODES);
    ushort_t* wht  = (ushort_t*)(ws + OFF_WH);     // [16][64][576]
    float* s1      = ws + OFF_S1;
    float* s2      = ws + OFF_S2;
    ushort_t* xbuf_bf = (ushort_t*)(ws + OFF_X);
    ushort_t* wht2 = (ushort_t*)(ws + OFF_WH2);    // [4][256][576]
    float* s1b     = ws + OFF_S1B;
    float* s2b     = ws + OFF_S2B;
    ushort_t* g_bf = (ushort_t*)(ws + OFF_G);
    float* sums    = ws + OFF_SUMS;
    ushort_t* bt   = (ushort_t*)(ws + OFF_BT);
    ushort_t* asegb = (ushort_t*)(ws + OFF_ASEG);  // bf16 [4][64][576]
    float* segb    = ws + OFF_SEG;
    ushort_t* rfb  = (ushort_t*)(ws + OFF_RFB);    // bf16 region_f
    ushort_t* wcomb = (ushort_t*)(ws + OFF_WCOMB);
    float* bias2v  = ws + OFF_B2;
    ushort_t* attnb = (ushort_t*)(ws + OFF_ATTNB);

    float* out_region = out;                    // (2048,1280)
    float* out_seg    = out + 2048L*1280;       // (4,54,400,608)
    ushort_t* stuffb  = (ushort_t*)out_seg;     // bf16 scratch, dead before resize

    // 0. pure streaming head: P+sums, stuff->bf16, attn softmax, weight prep, zeros
    stream_prep<<<13712, 256, 0, stream>>>(score, pb, sums, stuff, stuffb, attnb,
                                           region_f, out_region, rfb, W_seg, asegb,
                                           W_rin, W_sin, W_heads, W_gout, W_rout, W_sout,
                                           b_sout, bt, wcomb, bias2v, ccp, s1b);

    // 1. pure cc GEMM (bf16 operands, 3040 blocks, XCD-grouped, atomic split-K)
    cc_gemm<<<CCBLK, 256, 0, stream>>>(pb, stuffb, ccp);

    // 2. nodes (144) + seg512 fillers 0..79
    nodes_seg<<<224, 256, 0, stream>>>(
        rfb, bt + BT_RIN, ccp, sums, bt + BT_SIN, nodes_bf, b_rin, b_sin,
        stuffb, asegb, b_seg, segb);

    // 3. WhT + s1/s2 (144) + seg512 fillers 80..159
    wht_seg<<<224, 256, 0, stream>>>(
        nodes_bf, bt + BT_HEADS, wht, a_heads, s1, s2,
        stuffb, asegb, b_seg, segb);

    // 4. head attention (144) + seg512 fillers 160..239
    att64_seg<<<224, 256, 0, stream>>>(
        wht, s1, s2, xbuf_bf, stuffb, asegb, b_seg, segb);

    // 5. WhT2 + s1b/s2b (144) + seg512 fillers 240..319
    wht2_seg<<<224, 256, 0, stream>>>(
        xbuf_bf, bt + BT_GOUT, wht2, a_gout, s1b, s2b,
        stuffb, asegb, b_seg, segb);

    // 6. gout attention + M2 (36) + seg512 fillers 320..475
    attg_seg<<<192, 256, 0, stream>>>(
        wht2, s1b, s2b, g_bf, wcomb, bias2v, asegb + 512,
        stuffb, asegb, b_seg, segb);

    // 7. rout GEMM (128) + segK64 accumulate into segb (476)
    rout_segk<<<604, 256, 0, stream>>>(
        g_bf, bt + BT_ROUT, out_region + 1024, b_rout, attnb, asegb, segb);

    // 8. bilinear resize -> output1
    resize_v2_kernel<<<((long)NBATCH*SSD*400*152 + 255)/256, 256, 0, stream>>>(segb, out_seg);
}

// Round 14
// 267.867 us; speedup vs baseline: 1.0645x; 1.0110x over previous
//
#include <hip/hip_runtime.h>

#define HW 15200
#define SSD 54
#define NBATCH 4
#define NNODE 566
#define NPAD 576
#define CGD 256
#define CDD 512
#define NSPLIT 95
#define KSPAN 160   // 15200/95
#define NGRP (NSPLIT*NBATCH)          // 380
#define CCBLK 3072                    // ceil(380/8)*64
#define LDSROW 168                    // padded LDS row (elements): 336B, 2-way-bank-free

typedef __attribute__((ext_vector_type(4))) float f32x4;
typedef __attribute__((ext_vector_type(8))) short bf16x8;
typedef unsigned short ushort_t;

// BT sub-offsets (ushort units)
#define BT_RIN   0
#define BT_SIN   262144
#define BT_HEADS 393216
#define BT_GOUT  458752
#define BT_ROUT  524288
#define BT_SOUT  589824
#define BT_SEG2  622592
#define BT_TOTAL 630784

// ---------------- ws layout (float units) ----------------
static constexpr long OFF_P     = 0;                                    // pb bf16 [4][64][HW] (exp, unnormalized)
static constexpr long OFF_CC    = OFF_P     + (long)NBATCH*SSD*HW;      // fp32 ccp [4][64][512] (atomic acc)
static constexpr long OFF_NODES = OFF_CC    + (long)NBATCH*64*CDD;      // bf16 [4][566][256]
static constexpr long OFF_WH    = OFF_NODES + (long)NBATCH*NNODE*CGD;   // WhT bf16 [16][64][576]
static constexpr long OFF_S1    = OFF_WH    + (long)16*NNODE*64;
static constexpr long OFF_S2    = OFF_S1    + 16*NPAD;
static constexpr long OFF_X     = OFF_S2    + 16*NPAD;                  // bf16 [4][566][256]
static constexpr long OFF_WH2   = OFF_X     + (long)NBATCH*NNODE*CGD;   // WhT2 bf16 [4][256][576]
static constexpr long OFF_S1B   = OFF_WH2   + (long)NBATCH*NNODE*CGD;   // fp32 [4][576] (atomic acc)
static constexpr long OFF_S2B   = OFF_S1B   + NBATCH*NPAD;              // fp32 [4][576] (atomic acc)
static constexpr long OFF_G     = OFF_S2B   + NBATCH*NPAD;              // bf16 [4][566][256]
static constexpr long OFF_SUMS  = OFF_G     + (long)NBATCH*NNODE*CGD;   // fp32 [4][64] softmax row sums
static constexpr long OFF_BT    = OFF_SUMS  + 256;                      // bf16 transposed weights
static constexpr long OFF_ASEG  = OFF_BT    + (BT_TOTAL/2 + 8);         // bf16 Aseg [4][64][576]
static constexpr long OFF_SEG   = OFF_ASEG  + (long)NBATCH*64*576/2;    // segb fp32 [4][54][HW]
static constexpr long OFF_RFB   = OFF_SEG   + (long)NBATCH*SSD*HW;      // bf16 region_f [2048][1024]
static constexpr long OFF_WCOMB = OFF_RFB   + 1048576;                  // bf16 [64][256] W_sout@Wseg2 ^T
static constexpr long OFF_B2    = OFF_WCOMB + 8192;                     // fp32 [64] b_sout@Wseg2
static constexpr long OFF_ATTNB = OFF_B2    + 64;                       // bf16 attn [4][64][HW]

__device__ inline float lrelu04(float x){ return x >= 0.f ? x : 0.4f*x; }
__device__ inline float eluf(float x){ return x > 0.f ? x : __expf(x) - 1.f; }
__device__ inline ushort_t f2bf(float f){
    unsigned u = __float_as_uint(f);
    return (ushort_t)((u + 0x7FFFu + ((u >> 16) & 1u)) >> 16);
}
__device__ inline float bf2f(ushort_t u){ return __uint_as_float((unsigned)u << 16); }
__device__ inline bf16x8 pack8(float4 lo, float4 hi){
    union { bf16x8 v; ushort_t u[8]; } p;
    p.u[0]=f2bf(lo.x); p.u[1]=f2bf(lo.y); p.u[2]=f2bf(lo.z); p.u[3]=f2bf(lo.w);
    p.u[4]=f2bf(hi.x); p.u[5]=f2bf(hi.y); p.u[6]=f2bf(hi.z); p.u[7]=f2bf(hi.w);
    return p.v;
}

// ---------------- kernel 0: pure streaming head ----------------
// blk < 256:   P = exp(score) -> bf16 rows + fp32 row sums (plain store)
// blk >= 256:  stuff->bf16 convert, attn softmax, region copy, weight prep, zeros
#define SB_GIDS 1945600L   // 31,129,600 floats / 16 per thread
__global__ __launch_bounds__(256)
void stream_prep(const float* __restrict__ score, ushort_t* __restrict__ pb,
                 float* __restrict__ sums,
                 const float* __restrict__ stuff, ushort_t* __restrict__ stuffb,
                 ushort_t* __restrict__ attnb,
                 const float* __restrict__ rf, float* __restrict__ out_region,
                 ushort_t* __restrict__ rfb,
                 const float* __restrict__ W_seg, ushort_t* __restrict__ asegb,
                 const float* __restrict__ W_rin, const float* __restrict__ W_sin,
                 const float* __restrict__ W_heads, const float* __restrict__ W_gout,
                 const float* __restrict__ W_rout, const float* __restrict__ W_sout,
                 const float* __restrict__ b_sout,
                 ushort_t* __restrict__ bt, ushort_t* __restrict__ wcomb,
                 float* __restrict__ bias2,
                 float* __restrict__ ccp, float* __restrict__ s1s2b)
{
    int blk = blockIdx.x;
    int t = threadIdx.x;
    if (blk < 256) {
        int b = blk >> 6, s = blk & 63;
        ushort_t* prow = pb + ((long)b*64 + s)*HW;
        if (s >= SSD) {
            union { bf16x8 v; ushort_t u[8]; } z; 
            #pragma unroll
            for (int u = 0; u < 8; ++u) z.u[u] = 0;
            for (int i = t*8; i < HW; i += 2048) *(bf16x8*)&prow[i] = z.v;
            if (t == 0) sums[b*64 + s] = 1.f;
            return;
        }
        const float* row = score + ((long)b*SSD + s)*HW;
        __shared__ float red[4];
        float s_ = 0.f;
        for (int i = t*4; i < HW; i += 1024) {
            float4 x = *(const float4*)&row[i];
            x.x = __expf(x.x); x.y = __expf(x.y);
            x.z = __expf(x.z); x.w = __expf(x.w);
            s_ += x.x + x.y + x.z + x.w;
            union { ushort_t u[4]; uint2 q; } pk;
            pk.u[0]=f2bf(x.x); pk.u[1]=f2bf(x.y); pk.u[2]=f2bf(x.z); pk.u[3]=f2bf(x.w);
            *(uint2*)&prow[i] = pk.q;
        }
        #pragma unroll
        for (int off = 32; off >= 1; off >>= 1) s_ += __shfl_down(s_, off);
        if ((t & 63) == 0) red[t >> 6] = s_;
        __syncthreads();
        if (t == 0) sums[b*64 + s] = red[0] + red[1] + red[2] + red[3];
        return;
    }
    long gid = (long)(blk - 256)*256 + t;
    if (gid < SB_GIDS) {           // stuff fp32 -> stuffb bf16, fully coalesced
        long base = gid * 16;
        float4 v0 = *(const float4*)&stuff[base];
        float4 v1 = *(const float4*)&stuff[base + 4];
        float4 v2 = *(const float4*)&stuff[base + 8];
        float4 v3 = *(const float4*)&stuff[base + 12];
        *(bf16x8*)&stuffb[base]     = pack8(v0, v1);
        *(bf16x8*)&stuffb[base + 8] = pack8(v2, v3);
        return;
    }
    gid -= SB_GIDS;
    if (gid < (long)NBATCH*HW) {   // attn per-pixel softmax -> normalized bf16, 64 rows
        int b = (int)(gid / HW), n = (int)(gid % HW);
        const float* sp = score + (long)b*SSD*HW + n;
        float v[SSD];
        float m = -1e30f;
        #pragma unroll
        for (int s = 0; s < SSD; ++s) { v[s] = sp[(long)s*HW]; m = fmaxf(m, v[s]); }
        float sum = 0.f;
        #pragma unroll
        for (int s = 0; s < SSD; ++s) { v[s] = __expf(v[s] - m); sum += v[s]; }
        float inv = 1.f / sum;
        ushort_t* ap = attnb + (long)b*64*HW + n;
        #pragma unroll
        for (int s = 0; s < SSD; ++s) ap[(long)s*HW] = f2bf(v[s] * inv);
        #pragma unroll
        for (int s = SSD; s < 64; ++s) ap[(long)s*HW] = 0;
        return;
    }
    gid -= (long)NBATCH*HW;
    if (gid < 524288) {            // region_f copy (float4) + bf16 shadow
        long row = gid / 256, col = gid % 256;
        float4 v = reinterpret_cast<const float4*>(rf)[gid];
        reinterpret_cast<float4*>(out_region)[row*320 + col] = v;
        union { ushort_t u[4]; uint2 q; } pk;
        pk.u[0]=f2bf(v.x); pk.u[1]=f2bf(v.y); pk.u[2]=f2bf(v.z); pk.u[3]=f2bf(v.w);
        reinterpret_cast<uint2*>(rfb)[gid] = pk.q;
        return;
    }
    gid -= 524288;
    if (gid < 131072) {            // Aseg k<512: bf16 WsegT, 4 batch copies, zero-pad o>=54
        int b = (int)(gid >> 15);
        int r = (int)(gid & 32767);
        int o = r >> 9, k = r & 511;
        asegb[(long)b*36864 + (long)o*576 + k] = f2bf(o < SSD ? W_seg[k*SSD + o] : 0.f);
        return;
    }
    gid -= 131072;
    if (gid < BT_TOTAL) {
        int i = (int)gid;
        float v;
        if (i < BT_SIN)        { int j=i;            int n=j>>10, k=j&1023; v = W_rin[k*256+n]; }
        else if (i < BT_HEADS) { int j=i-BT_SIN;     int n=j>>9,  k=j&511;  v = W_sin[k*256+n]; }
        else if (i < BT_GOUT)  { int j=i-BT_HEADS;   int h=j>>14, r=j&16383; int f=r>>8, k=r&255;
                                 v = W_heads[(h*256+k)*64+f]; }
        else if (i < BT_ROUT)  { int j=i-BT_GOUT;    int n=j>>8,  k=j&255;  v = W_gout[k*256+n]; }
        else if (i < BT_SOUT)  { int j=i-BT_ROUT;    int n=j>>8,  k=j&255;  v = W_rout[k*256+n]; }
        else if (i < BT_SEG2)  { int j=i-BT_SOUT;    int n=j>>8,  k=j&255;  v = W_sout[k*128+n]; }
        else                   { int j=i-BT_SEG2;    int o=j>>7,  k=j&127;
                                 v = (o < SSD) ? W_seg[(512+k)*SSD + o] : 0.f; }
        bt[i] = f2bf(v);
        return;
    }
    gid -= BT_TOTAL;
    if (gid < 16384) {             // Wcomb^T[od][k] = sum_o W_sout[k,o] * Wseg2[o,od]
        int od = (int)(gid >> 8), k = (int)(gid & 255);
        float v = 0.f;
        if (od < SSD)
            for (int o = 0; o < 128; ++o)
                v += W_sout[k*128 + o] * W_seg[(512+o)*SSD + od];
        wcomb[(long)od*256 + k] = f2bf(v);
        return;
    }
    gid -= 16384;
    if (gid < 64) {                // bias2[od] = sum_o b_sout[o] * Wseg2[o,od]
        int od = (int)gid;
        float v = 0.f;
        if (od < SSD)
            for (int o = 0; o < 128; ++o)
                v += b_sout[o] * W_seg[(512+o)*SSD + od];
        bias2[od] = v;
        return;
    }
    gid -= 64;
    if (gid < 131072) { ccp[gid] = 0.f; return; }
    gid -= 131072;
    if (gid < 4608) s1s2b[gid] = 0.f;
}

// ---------------- kernel 1: cc GEMM with LDS-staged tiles (coalesced loads) ----------------
// 3040 active blocks, XCD-grouped. Each block stages its P[64][160] and S[64][160]
// bf16 tiles via fully-coalesced 320B-contiguous runs (row starts 64B-aligned),
// then runs the MFMA loop from LDS (row pad 168 el -> 2-way bank alias = free).
__global__ __launch_bounds__(256)
void cc_gemm(const ushort_t* __restrict__ pb, const ushort_t* __restrict__ stuffb,
             float* __restrict__ ccp)
{
    __shared__ ushort_t Pt[64][LDSROW];
    __shared__ ushort_t St[64][LDSROW];
    int bid = blockIdx.x;
    int g = (bid >> 6) * 8 + (bid & 7);    // group = (ks,b), 0..379 (+4 idle)
    if (g >= NGRP) return;
    int nt = (bid >> 3) & 7;
    int ks = g >> 2, b = g & 3;
    int t = threadIdx.x;
    int kbeg = ks * KSPAN;

    const ushort_t* Pg = pb + (long)b*64*HW + kbeg;
    const ushort_t* Sg = stuffb + ((long)b*CDD + nt*64)*HW + kbeg;
    #pragma unroll
    for (int i = 0; i < 5; ++i) {          // 1280 chunks of 8 bf16 per tile, 5/thread
        int c = t + i*256;
        int row = c / 20, kc = (c % 20) * 8;
        *(bf16x8*)&Pt[row][kc] = *(const bf16x8*)&Pg[(long)row*HW + kc];
        *(bf16x8*)&St[row][kc] = *(const bf16x8*)&Sg[(long)row*HW + kc];
    }
    __syncthreads();

    int w = t >> 6, l = t & 63;
    int lr = l & 15, lk = l >> 4;
    f32x4 acc[4] = {};
    #pragma unroll
    for (int k0 = 0; k0 < KSPAN; k0 += 32) {
        int kk = k0 + lk*8;
        bf16x8 sv = *(const bf16x8*)&St[w*16 + lr][kk];
        #pragma unroll
        for (int mi = 0; mi < 4; ++mi) {
            bf16x8 pv = *(const bf16x8*)&Pt[mi*16 + lr][kk];
            acc[mi] = __builtin_amdgcn_mfma_f32_16x16x32_bf16(pv, sv, acc[mi], 0, 0, 0);
        }
    }
    int c = nt*64 + w*16 + lr;
    #pragma unroll
    for (int mi = 0; mi < 4; ++mi)
        #pragma unroll
        for (int r = 0; r < 4; ++r) {
            int m = mi*16 + lk*4 + r;
            atomicAdd(&ccp[((long)b*64 + m)*CDD + c], acc[mi][r]);
        }
}

// ---------------- seg K-split bodies ----------------
__device__ __forceinline__
void seg512_body(int nt, int b,
                 const ushort_t* __restrict__ stuffb,
                 const ushort_t* __restrict__ asegb, const float* __restrict__ b_seg,
                 float* __restrict__ seg)
{
    int w = threadIdx.x >> 6, l = threadIdx.x & 63;
    int lr = l & 15, lk = l >> 4;
    int n0 = nt*128 + w*32;
    const ushort_t* A = asegb + (long)b*36864;
    const ushort_t* S = stuffb + (long)b*CDD*HW;
    f32x4 acc[4][2] = {};
    int n1 = min(n0 + lr, HW-1);
    int n2 = min(n0 + 16 + lr, HW-1);

    for (int k0 = 0; k0 < 512; k0 += 32) {
        const ushort_t* Bsrc = S + (long)k0*HW;
        long kb = (long)(lk*8)*HW;
        union { bf16x8 v; ushort_t u[8]; } b0, b1;
        #pragma unroll
        for (int u = 0; u < 8; ++u) {
            b0.u[u] = Bsrc[kb + (long)u*HW + n1];
            b1.u[u] = Bsrc[kb + (long)u*HW + n2];
        }
        #pragma unroll
        for (int ot = 0; ot < 4; ++ot) {
            bf16x8 af = *(const bf16x8*)&A[(ot*16 + lr)*576 + k0 + lk*8];
            acc[ot][0] = __builtin_amdgcn_mfma_f32_16x16x32_bf16(af, b0.v, acc[ot][0], 0,0,0);
            acc[ot][1] = __builtin_amdgcn_mfma_f32_16x16x32_bf16(af, b1.v, acc[ot][1], 0,0,0);
        }
    }

    #pragma unroll
    for (int ot = 0; ot < 4; ++ot) {
        #pragma unroll
        for (int r = 0; r < 4; ++r) {
            int o = ot*16 + lk*4 + r;
            if (o >= SSD) continue;
            float bb = b_seg[o];
            int na = n0 + lr, nb = n0 + 16 + lr;
            if (na < HW) seg[((long)b*SSD + o)*HW + na] = acc[ot][0][r] + bb;
            if (nb < HW) seg[((long)b*SSD + o)*HW + nb] = acc[ot][1][r] + bb;
        }
    }
}

__device__ __forceinline__
void segk64_body(int nt, int b,
                 const ushort_t* __restrict__ attnb,
                 const ushort_t* __restrict__ asegb,
                 float* __restrict__ seg)
{
    int w = threadIdx.x >> 6, l = threadIdx.x & 63;
    int lr = l & 15, lk = l >> 4;
    int n0 = nt*128 + w*32;
    const ushort_t* A = asegb + (long)b*36864;
    const ushort_t* T = attnb + (long)b*64*HW;
    f32x4 acc[4][2] = {};
    int n1 = min(n0 + lr, HW-1);
    int n2 = min(n0 + 16 + lr, HW-1);

    #pragma unroll
    for (int k0 = 512; k0 < 576; k0 += 32) {
        const ushort_t* Bsrc = T + (long)(k0-512)*HW;
        long kb = (long)(lk*8)*HW;
        union { bf16x8 v; ushort_t u[8]; } b0, b1;
        #pragma unroll
        for (int u = 0; u < 8; ++u) {
            b0.u[u] = Bsrc[kb + (long)u*HW + n1];
            b1.u[u] = Bsrc[kb + (long)u*HW + n2];
        }
        #pragma unroll
        for (int ot = 0; ot < 4; ++ot) {
            bf16x8 af = *(const bf16x8*)&A[(ot*16 + lr)*576 + k0 + lk*8];
            acc[ot][0] = __builtin_amdgcn_mfma_f32_16x16x32_bf16(af, b0.v, acc[ot][0], 0,0,0);
            acc[ot][1] = __builtin_amdgcn_mfma_f32_16x16x32_bf16(af, b1.v, acc[ot][1], 0,0,0);
        }
    }

    #pragma unroll
    for (int ot = 0; ot < 4; ++ot) {
        #pragma unroll
        for (int r = 0; r < 4; ++r) {
            int o = ot*16 + lk*4 + r;
            if (o >= SSD) continue;
            int na = n0 + lr, nb = n0 + 16 + lr;
            if (na < HW) { long i = ((long)b*SSD + o)*HW + na; seg[i] += acc[ot][0][r]; }
            if (nb < HW) { long i = ((long)b*SSD + o)*HW + nb; seg[i] += acc[ot][1][r]; }
        }
    }
}

// ---------------- barrier-free MFMA GEMM body ----------------
template<bool AF32, int OUTMODE>
__device__ __forceinline__
void mm_body(int bx, int by, int bz,
             const void* __restrict__ Ap, const ushort_t* __restrict__ Bt,
             void* __restrict__ Cp, const float* __restrict__ bias,
             int M, int N, int K, int lda, int ldc,
             long sA, int zdivA, long sB, int zmodB, long sC)
{
    int z = bz;
    int w = threadIdx.x >> 6, l = threadIdx.x & 63;
    int lr = l & 15, lk = l >> 4;
    int m0 = bx * 64 + w * 16;
    int n0 = by * 64;
    const ushort_t* bt = Bt + (long)(z % zmodB) * sB;
    int mload = min(m0 + lr, M - 1);
    const float*    Af = (const float*)Ap    + (long)(z / zdivA) * sA + (long)mload * lda;
    const ushort_t* Ab = (const ushort_t*)Ap + (long)(z / zdivA) * sA + (long)mload * lda;
    f32x4 acc[4] = {};

    #pragma unroll 2
    for (int k0 = 0; k0 < K; k0 += 32) {
        int kk = k0 + lk * 8;
        bf16x8 af;
        if (AF32) {
            float4 lo = *(const float4*)&Af[kk];
            float4 hi = *(const float4*)&Af[kk + 4];
            af = pack8(lo, hi);
        } else {
            af = *(const bf16x8*)&Ab[kk];
        }
        #pragma unroll
        for (int j = 0; j < 4; ++j) {
            bf16x8 bf = *(const bf16x8*)&bt[(long)(n0 + j*16 + lr) * K + kk];
            acc[j] = __builtin_amdgcn_mfma_f32_16x16x32_bf16(af, bf, acc[j], 0, 0, 0);
        }
    }

    #pragma unroll
    for (int j = 0; j < 4; ++j) {
        int n = n0 + j*16 + lr;
        float bb = bias ? bias[n] : 0.f;
        #pragma unroll
        for (int r = 0; r < 4; ++r) {
            int m = m0 + lk*4 + r;
            if (OUTMODE == 2) {
                float v = acc[j][r] + bb;
                ((ushort_t*)Cp)[(long)z * sC + (long)n * ldc + m] =
                    (m < M) ? f2bf(v) : (ushort_t)0;
            } else {
                if (m >= M) continue;
                float v = acc[j][r] + bb;
                if (OUTMODE == 0)
                    ((float*)Cp)[(long)z * sC + (long)m * ldc + n] = v;
                else
                    ((ushort_t*)Cp)[(long)z * sC + (long)m * ldc + n] = f2bf(v);
            }
        }
    }
}

// ---------------- nodes (144) + seg512 fillers (80, sid 0..79) ----------------
__global__ __launch_bounds__(256)
void nodes_seg(const ushort_t* __restrict__ rfb, const ushort_t* __restrict__ btRin,
               const float* __restrict__ ccp, const float* __restrict__ sums,
               const ushort_t* __restrict__ btSin, ushort_t* __restrict__ nodes,
               const float* __restrict__ b_rin, const float* __restrict__ b_sin,
               const ushort_t* __restrict__ stuffb, const ushort_t* __restrict__ asegb,
               const float* __restrict__ b_seg, float* __restrict__ segb)
{
    int bid = blockIdx.x;
    if (bid >= 144) {
        int sid = bid - 144;                    // 0..79
        seg512_body(sid % 119, sid / 119, stuffb, asegb, b_seg, segb);
        return;
    }
    int bx = bid % 9, by = (bid/9) % 4, bz = bid / 36;
    if (bx < 8) {
        mm_body<false, 1>(bx, by, bz, rfb, btRin, nodes, b_rin,
                          512, 256, 1024, 1024, 256, 512L*1024, 1, 0, 1, (long)NNODE*CGD);
        return;
    }
    int w = threadIdx.x >> 6, l = threadIdx.x & 63;
    int lr = l & 15, lk = l >> 4;
    int m0 = w * 16, n0 = by * 64;
    int mload = min(m0 + lr, SSD - 1);
    const float* Af = ccp + ((long)bz*64 + mload)*CDD;
    float inv = 1.f / sums[bz*64 + mload];
    f32x4 acc[4] = {};

    #pragma unroll 2
    for (int k0 = 0; k0 < CDD; k0 += 32) {
        int kk = k0 + lk * 8;
        float4 lo = *(const float4*)&Af[kk];
        float4 hi = *(const float4*)&Af[kk + 4];
        lo.x *= inv; lo.y *= inv; lo.z *= inv; lo.w *= inv;
        hi.x *= inv; hi.y *= inv; hi.z *= inv; hi.w *= inv;
        bf16x8 af = pack8(lo, hi);
        #pragma unroll
        for (int j = 0; j < 4; ++j) {
            bf16x8 bf = *(const bf16x8*)&btSin[(long)(n0 + j*16 + lr) * CDD + kk];
            acc[j] = __builtin_amdgcn_mfma_f32_16x16x32_bf16(af, bf, acc[j], 0, 0, 0);
        }
    }

    #pragma unroll
    for (int j = 0; j < 4; ++j) {
        int n = n0 + j*16 + lr;
        float bb = b_sin[n];
        #pragma unroll
        for (int r = 0; r < 4; ++r) {
            int m = m0 + lk*4 + r;
            if (m >= SSD) continue;
            nodes[(long)bz*NNODE*CGD + (long)(512 + m)*CGD + n] = f2bf(acc[j][r] + bb);
        }
    }
}

// ---------------- WhT heads + s1/s2 (144) + seg512 fillers (80, sid 80..159) ----------------
__global__ __launch_bounds__(256)
void wht_seg(const ushort_t* __restrict__ nodes, const ushort_t* __restrict__ btHeads,
             ushort_t* __restrict__ wht, const float* __restrict__ a_heads,
             float* __restrict__ s1, float* __restrict__ s2,
             const ushort_t* __restrict__ stuffb, const ushort_t* __restrict__ asegb,
             const float* __restrict__ b_seg, float* __restrict__ segb)
{
    int bid = blockIdx.x;
    if (bid >= 144) {
        int sid = bid - 144 + 80;
        seg512_body(sid % 119, sid / 119, stuffb, asegb, b_seg, segb);
        return;
    }
    int bx = bid % 9, z = bid / 9;                // z = b*4 + h
    int w = threadIdx.x >> 6, l = threadIdx.x & 63;
    int lr = l & 15, lk = l >> 4;
    int m0 = bx*64 + w*16;
    const ushort_t* bt = btHeads + (long)(z & 3) * (64L*256);
    int mload = min(m0 + lr, NNODE - 1);
    const ushort_t* Ab = nodes + (long)(z >> 2)*((long)NNODE*CGD) + (long)mload*CGD;
    f32x4 acc[4] = {};

    #pragma unroll 2
    for (int k0 = 0; k0 < 256; k0 += 32) {
        int kk = k0 + lk*8;
        bf16x8 af = *(const bf16x8*)&Ab[kk];
        #pragma unroll
        for (int j = 0; j < 4; ++j) {
            bf16x8 bf = *(const bf16x8*)&bt[(long)(j*16 + lr)*256 + kk];
            acc[j] = __builtin_amdgcn_mfma_f32_16x16x32_bf16(af, bf, acc[j], 0, 0, 0);
        }
    }

    const float* av = a_heads + (long)(z & 3)*128;
    ushort_t* Wout = wht + (long)z*(64L*NPAD);
    float p1[4] = {0.f,0.f,0.f,0.f}, p2[4] = {0.f,0.f,0.f,0.f};
    #pragma unroll
    for (int j = 0; j < 4; ++j) {
        int f = j*16 + lr;
        float c1 = av[f], c2 = av[64 + f];
        #pragma unroll
        for (int r = 0; r < 4; ++r) {
            int m = m0 + lk*4 + r;
            float v = acc[j][r];
            Wout[(long)f*NPAD + m] = (m < NNODE) ? f2bf(v) : (ushort_t)0;
            if (m < NNODE) { p1[r] += v*c1; p2[r] += v*c2; }
        }
    }
    #pragma unroll
    for (int r = 0; r < 4; ++r)
        #pragma unroll
        for (int off = 1; off < 16; off <<= 1) {
            p1[r] += __shfl_xor(p1[r], off);
            p2[r] += __shfl_xor(p2[r], off);
        }
    if (lr == 0) {
        #pragma unroll
        for (int r = 0; r < 4; ++r) {
            int m = m0 + lk*4 + r;
            if (m < NNODE) {
                s1[(long)z*NPAD + m] = p1[r];
                s2[(long)z*NPAD + m] = p2[r];
            }
        }
    }
}

// ---------------- MFMA attention body ----------------
template<int F, int HEADMODE>
__device__ __forceinline__
void att_body(int bx, int z, const ushort_t* __restrict__ WhTall,
              const float* __restrict__ s1v, const float* __restrict__ s2v,
              ushort_t* __restrict__ outbuf)
{
    constexpr int FT = F / 16;
    const ushort_t* W  = WhTall + (long)z * F * NPAD;
    const float* s1 = s1v + (long)z * NPAD;
    const float* s2 = s2v + (long)z * NPAD;
    int w = threadIdx.x >> 6, l = threadIdx.x & 63;
    int lr = l & 15, lk = l >> 4;

    __shared__ float s2sh[NPAD];
    __shared__ float redm[4];
    float mxl = -1e30f;
    for (int i = threadIdx.x; i < NPAD; i += 256) {
        float v = (i < NNODE) ? s2[i] : -1e30f;
        s2sh[i] = v;
        mxl = fmaxf(mxl, v);
    }
    #pragma unroll
    for (int off = 32; off >= 1; off >>= 1) mxl = fmaxf(mxl, __shfl_down(mxl, off));
    if (l == 0) redm[w] = mxl;
    __syncthreads();
    float s2max = fmaxf(fmaxf(redm[0], redm[1]), fmaxf(redm[2], redm[3]));

    int m0 = bx * 64 + w * 16;
    float s1r = s1[min(m0 + lr, NNODE - 1)];
    float mrow = lrelu04(s1r + s2max);

    union { bf16x8 v; ushort_t u[8]; } onesu;
    #pragma unroll
    for (int u = 0; u < 8; ++u) onesu.u[u] = 0x3F80;
    bf16x8 ones = onesu.v;

    f32x4 acc[FT] = {};
    f32x4 accw = {};

    for (int j0 = 0; j0 < NPAD; j0 += 32) {
        float wv[8];
        #pragma unroll
        for (int u = 0; u < 8; ++u) {
            float e = lrelu04(s1r + s2sh[j0 + lk*8 + u]);
            wv[u] = __expf(e - mrow);       // exactly 0 for padded j
        }
        float4 lo = {wv[0], wv[1], wv[2], wv[3]};
        float4 hi = {wv[4], wv[5], wv[6], wv[7]};
        bf16x8 af = pack8(lo, hi);
        accw = __builtin_amdgcn_mfma_f32_16x16x32_bf16(af, ones, accw, 0, 0, 0);
        #pragma unroll
        for (int ft = 0; ft < FT; ++ft) {
            bf16x8 bf = *(const bf16x8*)&W[(long)(ft*16 + lr)*NPAD + j0 + lk*8];
            acc[ft] = __builtin_amdgcn_mfma_f32_16x16x32_bf16(af, bf, acc[ft], 0, 0, 0);
        }
    }

    #pragma unroll
    for (int r = 0; r < 4; ++r) {
        int m = m0 + lk*4 + r;
        if (m >= NNODE) continue;
        float inv = 1.f / accw[r];
        #pragma unroll
        for (int ft = 0; ft < FT; ++ft) {
            int f = ft*16 + lr;
            float v = eluf(acc[ft][r] * inv);
            if (HEADMODE) {
                int b = z >> 2, h = z & 3;
                outbuf[((long)(b*NNODE + m))*CGD + h*64 + f] = f2bf(v);
            } else {
                outbuf[((long)(z*NNODE + m))*CGD + f] = f2bf(v);
            }
        }
    }
}

// ---------------- att64 (144) + seg512 fillers (80, sid 160..239) ----------------
__global__ __launch_bounds__(256)
void att64_seg(const ushort_t* __restrict__ wht, const float* __restrict__ s1,
               const float* __restrict__ s2, ushort_t* __restrict__ xbuf,
               const ushort_t* __restrict__ stuffb, const ushort_t* __restrict__ asegb,
               const float* __restrict__ b_seg, float* __restrict__ segb)
{
    int bid = blockIdx.x;
    if (bid >= 144) {
        int sid = bid - 144 + 160;
        seg512_body(sid % 119, sid / 119, stuffb, asegb, b_seg, segb);
        return;
    }
    att_body<64, 1>(bid % 9, bid / 9, wht, s1, s2, xbuf);
}

// ---------------- WhT2 + s1b/s2b (144) + seg512 fillers (80, sid 240..319) ----------------
__global__ __launch_bounds__(256)
void wht2_seg(const ushort_t* __restrict__ xbuf, const ushort_t* __restrict__ btGout,
              ushort_t* __restrict__ wht2, const float* __restrict__ a_gout,
              float* __restrict__ s1b, float* __restrict__ s2b,
              const ushort_t* __restrict__ stuffb, const ushort_t* __restrict__ asegb,
              const float* __restrict__ b_seg, float* __restrict__ segb)
{
    int bid = blockIdx.x;
    if (bid >= 144) {
        int sid = bid - 144 + 240;
        seg512_body(sid % 119, sid / 119, stuffb, asegb, b_seg, segb);
        return;
    }
    int bx = bid % 9, by = (bid/9) % 4, z = bid / 36;
    int w = threadIdx.x >> 6, l = threadIdx.x & 63;
    int lr = l & 15, lk = l >> 4;
    int m0 = bx*64 + w*16;
    int n0 = by*64;
    int mload = min(m0 + lr, NNODE - 1);
    const ushort_t* Ab = xbuf + (long)z*((long)NNODE*CGD) + (long)mload*CGD;
    f32x4 acc[4] = {};

    #pragma unroll 2
    for (int k0 = 0; k0 < 256; k0 += 32) {
        int kk = k0 + lk*8;
        bf16x8 af = *(const bf16x8*)&Ab[kk];
        #pragma unroll
        for (int j = 0; j < 4; ++j) {
            bf16x8 bf = *(const bf16x8*)&btGout[(long)(n0 + j*16 + lr)*256 + kk];
            acc[j] = __builtin_amdgcn_mfma_f32_16x16x32_bf16(af, bf, acc[j], 0, 0, 0);
        }
    }

    ushort_t* Wout = wht2 + (long)z*(256L*NPAD);
    float p1[4] = {0.f,0.f,0.f,0.f}, p2[4] = {0.f,0.f,0.f,0.f};
    #pragma unroll
    for (int j = 0; j < 4; ++j) {
        int f = n0 + j*16 + lr;
        float c1 = a_gout[f], c2 = a_gout[256 + f];
        #pragma unroll
        for (int r = 0; r < 4; ++r) {
            int m = m0 + lk*4 + r;
            float v = acc[j][r];
            Wout[(long)f*NPAD + m] = (m < NNODE) ? f2bf(v) : (ushort_t)0;
            if (m < NNODE) { p1[r] += v*c1; p2[r] += v*c2; }
        }
    }
    #pragma unroll
    for (int r = 0; r < 4; ++r)
        #pragma unroll
        for (int off = 1; off < 16; off <<= 1) {
            p1[r] += __shfl_xor(p1[r], off);
            p2[r] += __shfl_xor(p2[r], off);
        }
    if (lr == 0) {
        #pragma unroll
        for (int r = 0; r < 4; ++r) {
            int m = m0 + lk*4 + r;
            if (m < NNODE) {
                atomicAdd(&s1b[(long)z*NPAD + m], p1[r]);
                atomicAdd(&s2b[(long)z*NPAD + m], p2[r]);
            }
        }
    }
}

// ---------------- gout attention + M2 (36) + seg512 fillers (156, sid 320..475) ----------------
__global__ __launch_bounds__(256)
void attg_seg(const ushort_t* __restrict__ wht2, const float* __restrict__ s1v,
              const float* __restrict__ s2v, ushort_t* __restrict__ g,
              const ushort_t* __restrict__ wcomb, const float* __restrict__ bias2,
              ushort_t* __restrict__ asegm2,
              const ushort_t* __restrict__ stuffb, const ushort_t* __restrict__ asegb,
              const float* __restrict__ b_seg, float* __restrict__ segb)
{
    int bid = blockIdx.x;
    if (bid >= 36) {
        int sid = bid - 36 + 320;
        seg512_body(sid % 119, sid / 119, stuffb, asegb, b_seg, segb);
        return;
    }
    int bx = bid % 9, z = bid / 9;
    const ushort_t* W  = wht2 + (long)z * (256L*NPAD);
    const float* s1 = s1v + (long)z * NPAD;
    const float* s2 = s2v + (long)z * NPAD;
    int t = threadIdx.x;
    int w = t >> 6, l = t & 63;
    int lr = l & 15, lk = l >> 4;

    __shared__ float s2sh[NPAD];
    __shared__ float redm[4];
    __shared__ ushort_t gld[64][264];   // class-rows stage for M2 (bx==8 only)

    float mxl = -1e30f;
    for (int i = t; i < NPAD; i += 256) {
        float v = (i < NNODE) ? s2[i] : -1e30f;
        s2sh[i] = v;
        mxl = fmaxf(mxl, v);
    }
    if (bx == 8)   // rows >= 54 (nodes >= 566) never staged below
        for (int i = t; i < 10*264; i += 256) gld[54 + i/264][i%264] = 0;
    #pragma unroll
    for (int off = 32; off >= 1; off >>= 1) mxl = fmaxf(mxl, __shfl_down(mxl, off));
    if (l == 0) redm[w] = mxl;
    __syncthreads();
    float s2max = fmaxf(fmaxf(redm[0], redm[1]), fmaxf(redm[2], redm[3]));

    int m0 = bx * 64 + w * 16;
    float s1r = s1[min(m0 + lr, NNODE - 1)];
    float mrow = lrelu04(s1r + s2max);

    union { bf16x8 v; ushort_t u[8]; } onesu;
    #pragma unroll
    for (int u = 0; u < 8; ++u) onesu.u[u] = 0x3F80;
    bf16x8 ones = onesu.v;

    f32x4 acc[16] = {};
    f32x4 accw = {};

    for (int j0 = 0; j0 < NPAD; j0 += 32) {
        float wv[8];
        #pragma unroll
        for (int u = 0; u < 8; ++u) {
            float e = lrelu04(s1r + s2sh[j0 + lk*8 + u]);
            wv[u] = __expf(e - mrow);
        }
        float4 lo = {wv[0], wv[1], wv[2], wv[3]};
        float4 hi = {wv[4], wv[5], wv[6], wv[7]};
        bf16x8 af = pack8(lo, hi);
        accw = __builtin_amdgcn_mfma_f32_16x16x32_bf16(af, ones, accw, 0, 0, 0);
        #pragma unroll
        for (int ft = 0; ft < 16; ++ft) {
            bf16x8 bf = *(const bf16x8*)&W[(long)(ft*16 + lr)*NPAD + j0 + lk*8];
            acc[ft] = __builtin_amdgcn_mfma_f32_16x16x32_bf16(af, bf, acc[ft], 0, 0, 0);
        }
    }

    #pragma unroll
    for (int r = 0; r < 4; ++r) {
        int m = m0 + lk*4 + r;
        if (m >= NNODE) continue;
        float inv = 1.f / accw[r];
        #pragma unroll
        for (int ft = 0; ft < 16; ++ft) {
            int f = ft*16 + lr;
            ushort_t vb = f2bf(eluf(acc[ft][r] * inv));
            g[((long)(z*NNODE + m))*CGD + f] = vb;
            if (bx == 8) gld[m - 512][f] = vb;
        }
    }

    if (bx == 8) {  // M2^T = (g_class @ Wcomb)^T + bias2 -> Aseg[:, :, 512:576]
        __syncthreads();
        f32x4 acc2[4] = {};
        #pragma unroll 2
        for (int k0 = 0; k0 < 256; k0 += 32) {
            int kk = k0 + lk*8;
            bf16x8 af = *(const bf16x8*)&gld[w*16 + lr][kk];
            #pragma unroll
            for (int j = 0; j < 4; ++j) {
                bf16x8 bf = *(const bf16x8*)&wcomb[(long)(j*16 + lr)*256 + kk];
                acc2[j] = __builtin_amdgcn_mfma_f32_16x16x32_bf16(af, bf, acc2[j], 0, 0, 0);
            }
        }
        #pragma unroll
        for (int j = 0; j < 4; ++j) {
            int n = j*16 + lr;
            float bb = bias2[n];
            #pragma unroll
            for (int r = 0; r < 4; ++r) {
                int m = w*16 + lk*4 + r;
                asegm2[(long)z*36864 + (long)n*576 + m] =
                    (m < SSD) ? f2bf(acc2[j][r] + bb) : (ushort_t)0;
            }
        }
    }
}

// ---------------- rout GEMM (128) + segK64 accumulate (476) ----------------
__global__ __launch_bounds__(256)
void rout_segk(const ushort_t* __restrict__ g_bf, const ushort_t* __restrict__ btRout,
               float* __restrict__ outreg, const float* __restrict__ b_rout,
               const ushort_t* __restrict__ attnb, const ushort_t* __restrict__ asegb,
               float* __restrict__ segb)
{
    int bid = blockIdx.x;
    if (bid < 128) {
        int x = bid & 7, y = (bid >> 3) & 3, z = bid >> 5;
        mm_body<false, 0>(x, y, z, g_bf, btRout, outreg, b_rout,
                          512, 256, 256, 256, 1280, (long)NNODE*CGD, 1, 0, 1, 512L*1280);
    } else {
        int sid = bid - 128;
        segk64_body(sid % 119, sid / 119, attnb, asegb, segb);
    }
}

// ---------------- bilinear 4x upsample ----------------
__global__ __launch_bounds__(256)
void resize_v2_kernel(const float* __restrict__ seg, float* __restrict__ out)
{
    long u = (long)blockIdx.x * 256 + threadIdx.x;
    const long TOT4 = (long)NBATCH * SSD * 400 * 152;
    if (u >= TOT4) return;
    int m = (int)(u % 152);
    long r = u / 152;
    int y = (int)(r % 400);
    long c = r / 400;
    float fy = y * 0.25f - 0.375f;
    int y0 = (int)floorf(fy);
    float wy = fy - (float)y0;
    int y0c = max(y0, 0), y1c = min(y0 + 1, 99);
    const float* sp = seg + c * HW;
    int xm = max(m - 1, 0), xp = min(m + 1, 151);
    float r0a = sp[y0c * 152 + xm], r0b = sp[y0c * 152 + m], r0c = sp[y0c * 152 + xp];
    float r1a = sp[y1c * 152 + xm], r1b = sp[y1c * 152 + m], r1c = sp[y1c * 152 + xp];
    float ra = r0a + wy * (r1a - r0a);
    float rb = r0b + wy * (r1b - r0b);
    float rc = r0c + wy * (r1c - r0c);
    float4 o4;
    o4.x = 0.375f * ra + 0.625f * rb;
    o4.y = 0.125f * ra + 0.875f * rb;
    o4.z = 0.875f * rb + 0.125f * rc;
    o4.w = 0.625f * rb + 0.375f * rc;
    reinterpret_cast<float4*>(out)[u] = o4;
}

// ---------------- host ----------------
extern "C" void kernel_launch(void* const* d_in, const int* in_sizes, int n_in,
                              void* d_out, int out_size, void* d_ws, size_t ws_size,
                              hipStream_t stream)
{
    const float* region_f = (const float*)d_in[0];
    const float* stuff    = (const float*)d_in[1];
    const float* score    = (const float*)d_in[2];
    const float* W_rin    = (const float*)d_in[3];
    const float* b_rin    = (const float*)d_in[4];
    const float* W_sin    = (const float*)d_in[5];
    const float* b_sin    = (const float*)d_in[6];
    const float* W_heads  = (const float*)d_in[7];
    const float* a_heads  = (const float*)d_in[8];
    const float* W_gout   = (const float*)d_in[9];
    const float* a_gout   = (const float*)d_in[10];
    const float* W_rout   = (const float*)d_in[11];
    const float* b_rout   = (const float*)d_in[12];
    const float* W_sout   = (const float*)d_in[13];
    const float* b_sout   = (const float*)d_in[14];
    const float* W_seg    = (const float*)d_in[15];
    const float* b_seg    = (const float*)d_in[16];

    float* out = (float*)d_out;
    float* ws  = (float*)d_ws;

    ushort_t* pb   = (ushort_t*)(ws + OFF_P);
    float* ccp     = ws + OFF_CC;
    ushort_t* nodes_bf = (ushort_t*)(ws + OFF_NODES);
    ushort_t* wht  = (ushort_t*)(ws + OFF_WH);     // [16][64][576]
    float* s1      = ws + OFF_S1;
    float* s2      = ws + OFF_S2;
    ushort_t* xbuf_bf = (ushort_t*)(ws + OFF_X);
    ushort_t* wht2 = (ushort_t*)(ws + OFF_WH2);    // [4][256][576]
    float* s1b     = ws + OFF_S1B;
    float* s2b     = ws + OFF_S2B;
    ushort_t* g_bf = (ushort_t*)(ws + OFF_G);
    float* sums    = ws + OFF_SUMS;
    ushort_t* bt   = (ushort_t*)(ws + OFF_BT);
    ushort_t* asegb = (ushort_t*)(ws + OFF_ASEG);  // bf16 [4][64][576]
    float* segb    = ws + OFF_SEG;
    ushort_t* rfb  = (ushort_t*)(ws + OFF_RFB);    // bf16 region_f
    ushort_t* wcomb = (ushort_t*)(ws + OFF_WCOMB);
    float* bias2v  = ws + OFF_B2;
    ushort_t* attnb = (ushort_t*)(ws + OFF_ATTNB);

    float* out_region = out;                    // (2048,1280)
    float* out_seg    = out + 2048L*1280;       // (4,54,400,608)
    ushort_t* stuffb  = (ushort_t*)out_seg;     // bf16 scratch, dead before resize

    // 0. pure streaming head: P+sums, stuff->bf16, attn softmax, weight prep, zeros
    stream_prep<<<13712, 256, 0, stream>>>(score, pb, sums, stuff, stuffb, attnb,
                                           region_f, out_region, rfb, W_seg, asegb,
                                           W_rin, W_sin, W_heads, W_gout, W_rout, W_sout,
                                           b_sout, bt, wcomb, bias2v, ccp, s1b);

    // 1. cc GEMM with LDS-staged tiles (coalesced loads, 3040 blocks, XCD-grouped)
    cc_gemm<<<CCBLK, 256, 0, stream>>>(pb, stuffb, ccp);

    // 2. nodes (144) + seg512 fillers 0..79
    nodes_seg<<<224, 256, 0, stream>>>(
        rfb, bt + BT_RIN, ccp, sums, bt + BT_SIN, nodes_bf, b_rin, b_sin,
        stuffb, asegb, b_seg, segb);

    // 3. WhT + s1/s2 (144) + seg512 fillers 80..159
    wht_seg<<<224, 256, 0, stream>>>(
        nodes_bf, bt + BT_HEADS, wht, a_heads, s1, s2,
        stuffb, asegb, b_seg, segb);

    // 4. head attention (144) + seg512 fillers 160..239
    att64_seg<<<224, 256, 0, stream>>>(
        wht, s1, s2, xbuf_bf, stuffb, asegb, b_seg, segb);

    // 5. WhT2 + s1b/s2b (144) + seg512 fillers 240..319
    wht2_seg<<<224, 256, 0, stream>>>(
        xbuf_bf, bt + BT_GOUT, wht2, a_gout, s1b, s2b,
        stuffb, asegb, b_seg, segb);

    // 6. gout attention + M2 (36) + seg512 fillers 320..475
    attg_seg<<<192, 256, 0, stream>>>(
        wht2, s1b, s2b, g_bf, wcomb, bias2v, asegb + 512,
        stuffb, asegb, b_seg, segb);

    // 7. rout GEMM (128) + segK64 accumulate into segb (476)
    rout_segk<<<604, 256, 0, stream>>>(
        g_bf, bt + BT_ROUT, out_region + 1024, b_rout, attnb, asegb, segb);

    // 8. bilinear resize -> output1
    resize_v2_kernel<<<((long)NBATCH*SSD*400*152 + 255)/256, 256, 0, stream>>>(segb, out_seg);
}